// Round 7
// baseline (707.450 us; speedup 1.0000x reference)
//
#include <hip/hip_runtime.h>
#include <hip/hip_bf16.h>
#include <math.h>

// Problem constants
#define A_N    2000
#define P_N    20000
#define E_N    200000
#define MUL0   128
#define MUL1   64
#define DIM    320     // MUL0 + 3*MUL1
#define NBASIS 10
#define FC_HID 100
#define WNUM   384     // 128+128+64+64
#define MID0   192     // MUL0 + MUL1
#define RDIM   768
#define RT     16      // receivers per block (fused kernel)

// scales
#define RS10   0.31622776601683794f
#define RS100  0.1f
#define RS128  0.08838834764831845f
#define RS64   0.125f
#define RS192  0.07216878364870323f
#define RS3    0.5773502691896258f
#define RSNEI  0.31622776601683794f

typedef __bf16 bf16x8 __attribute__((ext_vector_type(8)));
typedef float  f32x4  __attribute__((ext_vector_type(4)));

// ---------------------------------------------------------------------------
// Kernel 1: sender transform -> bf16 s0h/s1h (proven R3-R6)
// ---------------------------------------------------------------------------
__global__ __launch_bounds__(320) void sender_kernel(
    const float* __restrict__ sender_input, const float* __restrict__ sender_attr,
    const float* __restrict__ lin1_w0, const float* __restrict__ lin1_w1,
    __hip_bfloat16* __restrict__ s0h, __hip_bfloat16* __restrict__ s1h)
{
    __shared__ float sin_s[DIM];
    const int a = blockIdx.x;
    const int t = threadIdx.x;
    const float attr = sender_attr[a];
    sin_s[t] = sender_input[(size_t)a * DIM + t] * attr;
    __syncthreads();
    if (t < MUL0) {
        float acc = 0.f;
        for (int u = 0; u < MUL0; ++u)
            acc = fmaf(sin_s[u], lin1_w0[u * MUL0 + t], acc);
        s0h[(size_t)a * MUL0 + t] = __float2bfloat16(acc * RS128);
    } else {
        const int idx = t - MUL0;
        const int v = idx / 3, m = idx - 3 * v;
        float acc = 0.f;
        for (int u = 0; u < MUL1; ++u)
            acc = fmaf(sin_s[MUL0 + 3 * u + m], lin1_w1[u * MUL1 + v], acc);
        s1h[(size_t)a * 192 + idx] = __float2bfloat16(acc * RS64);
    }
}

// ---------------------------------------------------------------------------
// CSR build: histogram -> scan -> scatter   (proven R3-R6)
// ---------------------------------------------------------------------------
__global__ __launch_bounds__(256) void hist_kernel(
    const int* __restrict__ edge_dst, int* __restrict__ counts)
{
    const int e = blockIdx.x * 256 + threadIdx.x;
    if (e < E_N) atomicAdd(&counts[edge_dst[e]], 1);
}

__global__ __launch_bounds__(1024) void scan_kernel(
    const int* __restrict__ counts, int* __restrict__ head)
{
    __shared__ int part[1024];
    const int t = threadIdx.x;
    const int base = t * 20;
    int c[20];
    int s = 0;
    #pragma unroll
    for (int i = 0; i < 20; ++i) {
        const int p = base + i;
        c[i] = (p < P_N) ? counts[p] : 0;
        s += c[i];
    }
    part[t] = s;
    __syncthreads();
    for (int off = 1; off < 1024; off <<= 1) {
        const int v = (t >= off) ? part[t - off] : 0;
        __syncthreads();
        part[t] += v;
        __syncthreads();
    }
    int run = (t > 0) ? part[t - 1] : 0;
    #pragma unroll
    for (int i = 0; i < 20; ++i) {
        const int p = base + i;
        if (p < P_N) { head[p] = run; run += c[i]; }
    }
}

__global__ __launch_bounds__(256) void scatter_kernel(
    const int* __restrict__ edge_dst, int* __restrict__ head,
    int* __restrict__ sorted)
{
    const int e = blockIdx.x * 256 + threadIdx.x;
    if (e < E_N) {
        const int pos = atomicAdd(&head[edge_dst[e]], 1);
        sorted[pos] = e;
    }
}

// ---------------------------------------------------------------------------
// Generic pack: src [K][N] f32 row-major -> bf16 MFMA B-fragment order
// (same layout as R6's proven w2pack). frag fi = n*KG + g; lane l elem i:
// k = g*32 + 8*(l>>4) + i, col = n*16 + (l&15); zero-pad k >= K.
// ---------------------------------------------------------------------------
__global__ __launch_bounds__(256) void pack_kernel(
    const float* __restrict__ src, __bf16* __restrict__ dst,
    int K, int KG, int N, float scale)
{
    const int tid  = blockIdx.x * 256 + threadIdx.x;
    const int lane = tid & 63;
    const int fi   = tid >> 6;
    const int g    = fi % KG;
    const int n    = fi / KG;
    const int col  = n * 16 + (lane & 15);
    const int kb   = g * 32 + 8 * (lane >> 4);
    bf16x8 v;
    #pragma unroll
    for (int i = 0; i < 8; ++i) {
        const int k = kb + i;
        v[i] = (__bf16)((k < K) ? src[(size_t)k * N + col] * scale : 0.f);
    }
    ((bf16x8*)dst)[tid] = v;
}

// ---------------------------------------------------------------------------
// FUSED kernel: per block = 16 receivers = one contiguous sorted-range.
// Tile loop (64 edges): stage es/eid -> h (MLP, bf16, swizzled LDS, proven R6)
// -> weight MFMA into w_lds (proven R6 frag layouts) -> consume into acc.
// Epilogue: rr/rin staged bf16+swizzle -> angle -> output via MFMA.
// ---------------------------------------------------------------------------
__global__ __launch_bounds__(256) void fused_kernel(
    const int* __restrict__ sorted, const int* __restrict__ head,
    const int* __restrict__ counts,
    const int* __restrict__ edge_src, const float* __restrict__ edge_attr,
    const float* __restrict__ edge_scalars,
    const float* __restrict__ fc_w1, const __bf16* __restrict__ w2p,
    const __bf16* __restrict__ scw0p, const __bf16* __restrict__ scw1p,
    const __bf16* __restrict__ l2w0p, const __bf16* __restrict__ l2w1p,
    const __hip_bfloat16* __restrict__ s0h, const __hip_bfloat16* __restrict__ s1h,
    const float* __restrict__ receiver_input, const float* __restrict__ receiver_attr,
    const float* __restrict__ lin3_w, float* __restrict__ out)
{
    __shared__ float fc1s[NBASIS * FC_HID];                 // 4 KB, resident
    __shared__ float es_s[64][NBASIS];                      // 2.5 KB
    __shared__ int   eid_s[64];
    __shared__ float cs_s[RT], sn_s[RT], rattr_s[RT];
    __shared__ __attribute__((aligned(16))) char buf[65536];
    // phase1: h_lds [64*128] bf16 @0 (16 KB) | w_lds [64][384] bf16 @16384 (48 KB)
    // phase2: rr0 [16][192] @0 | rr1 [3][16][192] @6144 | rin0 [16][128] @24576
    //         | rin1 [3][16][64] @28672   (34.8 KB total)

    const int tid  = threadIdx.x;
    const int wave = tid >> 6;
    const int lane = tid & 63;
    const int p0   = blockIdx.x * RT;

    int rstart[4], rend[4];
    #pragma unroll
    for (int r = 0; r < 4; ++r) {
        const int p = p0 + wave * 4 + r;
        const int c = counts[p], h = head[p];
        rstart[r] = h - c; rend[r] = h;          // head = segment end
    }
    const int blkStart = head[p0] - counts[p0];
    const int blkEnd   = head[p0 + RT - 1];
    const int nT = (blkEnd - blkStart + 63) >> 6;

    for (int i = tid; i < NBASIS * FC_HID; i += 256) fc1s[i] = fc_w1[i];
    if (tid < RT) rattr_s[tid] = receiver_attr[p0 + tid];

    float acc[4][12];
    #pragma unroll
    for (int r = 0; r < 4; ++r)
        #pragma unroll
        for (int i = 0; i < 12; ++i) acc[r][i] = 0.f;

    __bf16* h_lds = (__bf16*)buf;
    __bf16* w_lds = (__bf16*)(buf + 16384);

    for (int t = 0; t < nT; ++t) {
        const int tStart = blkStart + t * 64;
        const int tEnd   = tStart + 64;

        __syncthreads();   // protect eid/es/h/w from previous tile's consumers
        // stage eid + es (pad positions clamped; never consumed)
        if (tid < 64) {
            int gi = tStart + tid; if (gi >= E_N) gi = E_N - 1;
            eid_s[tid] = sorted[gi];
        }
        for (int f = tid; f < 64 * NBASIS; f += 256) {
            const int e = f / NBASIS, i = f - e * NBASIS;
            int gi = tStart + e; if (gi >= E_N) gi = E_N - 1;
            es_s[e][i] = edge_scalars[(size_t)sorted[gi] * NBASIS + i];
        }
        __syncthreads();

        // h: thread -> edge tid>>2, k-range (tid&3)*32..+31 (proven R6)
        {
            const int e  = tid >> 2;
            const int k0 = (tid & 3) * 32;
            float es[NBASIS];
            #pragma unroll
            for (int i = 0; i < NBASIS; ++i) es[i] = es_s[e][i];
            #pragma unroll
            for (int o = 0; o < 4; ++o) {
                bf16x8 hv;
                #pragma unroll
                for (int j = 0; j < 8; ++j) {
                    const int k = k0 + o * 8 + j;
                    float x = 0.f;
                    if (k < FC_HID) {
                        #pragma unroll
                        for (int i = 0; i < NBASIS; ++i)
                            x = fmaf(es[i], fc1s[i * FC_HID + k], x);
                        x *= RS10;
                        x = x / (1.f + __expf(-x));
                    }
                    hv[j] = (__bf16)x;
                }
                const int idx = (e * 128 + k0 + o * 8) ^ ((e & 7) << 3);
                *(bf16x8*)&h_lds[idx] = hv;
            }
        }
        __syncthreads();

        // weight MFMA: wave owns n-tiles [6w, 6w+6). nt-outer / a-reload keeps
        // register pressure low (acc[4][12] stays resident, no spill).
        {
            const int arow = lane & 15, ag = lane >> 4;
            const int row0 = 4 * (lane >> 4), col16 = lane & 15;
            for (int nt = 0; nt < 6; ++nt) {
                const int ntile = wave * 6 + nt;
                bf16x8 b[4];
                #pragma unroll
                for (int g = 0; g < 4; ++g)
                    b[g] = ((const bf16x8*)w2p)[(ntile * 4 + g) * 64 + lane];
                #pragma unroll
                for (int mt = 0; mt < 4; ++mt) {
                    f32x4 wa = {0.f, 0.f, 0.f, 0.f};
                    #pragma unroll
                    for (int g = 0; g < 4; ++g) {
                        const int e = mt * 16 + arow;
                        const int idx = (e * 128 + g * 32 + ag * 8) ^ ((e & 7) << 3);
                        bf16x8 a = *(const bf16x8*)&h_lds[idx];
                        wa = __builtin_amdgcn_mfma_f32_16x16x32_bf16(a, b[g], wa, 0, 0, 0);
                    }
                    __bf16* wr = &w_lds[(mt * 16 + row0) * WNUM + ntile * 16 + col16];
                    #pragma unroll
                    for (int j = 0; j < 4; ++j)
                        wr[j * WNUM] = (__bf16)wa[j];
                }
            }
        }
        __syncthreads();

        // consume this tile's edges into per-receiver acc (proven R4-R6 body)
        #pragma unroll
        for (int r = 0; r < 4; ++r) {
            const int lo = rstart[r] > tStart ? rstart[r] : tStart;
            const int hi = rend[r]   < tEnd   ? rend[r]   : tEnd;
            for (int pos = lo; pos < hi; ++pos) {
                const int i = pos - tStart;
                const int eid = eid_s[i];
                const __bf16* wr = &w_lds[i * WNUM];
                const float w0a = (float)wr[lane];
                const float w0b = (float)wr[64 + lane];
                const float w1a = (float)wr[128 + lane];
                const float w1b = (float)wr[192 + lane];
                const float w2v = (float)wr[256 + lane];
                const float w3v = (float)wr[320 + lane];

                const int src = edge_src[eid];
                const float4 ea = ((const float4*)edge_attr)[eid];
                const float sh0 = ea.x, sh1x = ea.y, sh1y = ea.z, sh1z = ea.w;

                const float g0a = __bfloat162float(s0h[(size_t)src * MUL0 + lane]);
                const float g0b = __bfloat162float(s0h[(size_t)src * MUL0 + 64 + lane]);
                const float g1x = __bfloat162float(s1h[(size_t)src * 192 + 3 * lane + 0]);
                const float g1y = __bfloat162float(s1h[(size_t)src * 192 + 3 * lane + 1]);
                const float g1z = __bfloat162float(s1h[(size_t)src * 192 + 3 * lane + 2]);

                acc[r][0] = fmaf(w0a * g0a, sh0, acc[r][0]);
                acc[r][1] = fmaf(w0b * g0b, sh0, acc[r][1]);
                const float dotg = fmaf(g1x, sh1x, fmaf(g1y, sh1y, g1z * sh1z)) * RS3;
                acc[r][2] = fmaf(w3v, dotg, acc[r][2]);
                const float p1a = w1a * g0a, p1b = w1b * g0b;
                acc[r][3] = fmaf(p1a, sh1x, acc[r][3]);
                acc[r][4] = fmaf(p1a, sh1y, acc[r][4]);
                acc[r][5] = fmaf(p1a, sh1z, acc[r][5]);
                acc[r][6] = fmaf(p1b, sh1x, acc[r][6]);
                acc[r][7] = fmaf(p1b, sh1y, acc[r][7]);
                acc[r][8] = fmaf(p1b, sh1z, acc[r][8]);
                const float q = w2v * sh0;
                acc[r][9]  = fmaf(q, g1x, acc[r][9]);
                acc[r][10] = fmaf(q, g1y, acc[r][10]);
                acc[r][11] = fmaf(q, g1z, acc[r][11]);
            }
        }
    }

    __syncthreads();   // all consume done; buf reused for rr/rin (phase2)

    __bf16* rr0  = (__bf16*)buf;             // [16][192]  r cols 0..191
    __bf16* rr1  = (__bf16*)(buf + 6144);    // [3][16][192] de-interleaved r1
    __bf16* rin0 = (__bf16*)(buf + 24576);   // [16][128]
    __bf16* rin1 = (__bf16*)(buf + 28672);   // [3][16][64]

    // stage rr (scaled, bf16, row-swizzled: elem-index bits 3..5 ^= row&7)
    #pragma unroll
    for (int r = 0; r < 4; ++r) {
        const int row = wave * 4 + r;
        const float rfac = RSNEI * rattr_s[row];
        const int sw = (row & 7) << 3;
        rr0[row * 192 + (lane ^ sw)]         = (__bf16)(acc[r][0] * rfac);
        rr0[row * 192 + ((64 + lane) ^ sw)]  = (__bf16)(acc[r][1] * rfac);
        rr0[row * 192 + ((128 + lane) ^ sw)] = (__bf16)(acc[r][2] * rfac);
        #pragma unroll
        for (int m = 0; m < 3; ++m) {
            __bf16* rr1m = rr1 + (m * 16 + row) * 192;
            rr1m[lane ^ sw]         = (__bf16)(acc[r][3 + m] * rfac);
            rr1m[(64 + lane) ^ sw]  = (__bf16)(acc[r][6 + m] * rfac);
            rr1m[(128 + lane) ^ sw] = (__bf16)(acc[r][9 + m] * rfac);
        }
    }
    // stage rin (scaled receiver_input, bf16, swizzled)
    for (int idx = tid; idx < RT * 128; idx += 256) {
        const int row = idx >> 7, c = idx & 127;
        const float v = receiver_input[(size_t)(p0 + row) * DIM + c] * rattr_s[row];
        rin0[row * 128 + (c ^ ((row & 7) << 3))] = (__bf16)v;
    }
    for (int idx = tid; idx < 3 * RT * 64; idx += 256) {
        const int m = idx >> 10, rem = idx & 1023;
        const int row = rem >> 6, u = rem & 63;
        const float v = receiver_input[(size_t)(p0 + row) * DIM + MUL0 + 3 * u + m]
                        * rattr_s[row];
        rin1[(m * 16 + row) * 64 + (u ^ ((row & 7) << 3))] = (__bf16)v;
    }
    __syncthreads();

    // angle: 16 receivers x 8 lanes
    if (tid < 128) {
        const int pw = tid >> 3, i0 = tid & 7, sw = (pw & 7) << 3;
        float a = 0.f;
        for (int u = i0; u < MID0; u += 8)
            a = fmaf((float)rr0[pw * 192 + (u ^ sw)], lin3_w[u], a);
        a += __shfl_xor(a, 1);
        a += __shfl_xor(a, 2);
        a += __shfl_xor(a, 4);
        if (i0 == 0) {
            a *= 0.1f * RS192;
            cs_s[pw] = __cosf(a);
            sn_s[pw] = __sinf(a);
        }
    }
    __syncthreads();

    // output via MFMA (scales folded into packs)
    const int crow0 = 4 * (lane >> 4), ccol = lane & 15;
    const int frow = lane & 15, fg = lane >> 4;
    const int fsw = (frow & 7) << 3;

    // scalar part: 8 n-tiles of 16 cols; wave w -> nt = 2w, 2w+1
    #pragma unroll
    for (int q = 0; q < 2; ++q) {
        const int nt = wave * 2 + q;
        f32x4 asc = {0.f, 0.f, 0.f, 0.f}, acv = {0.f, 0.f, 0.f, 0.f};
        #pragma unroll
        for (int g = 0; g < 4; ++g) {
            bf16x8 a = *(const bf16x8*)&rin0[frow * 128 + ((g * 32 + fg * 8) ^ fsw)];
            bf16x8 b = ((const bf16x8*)scw0p)[(nt * 4 + g) * 64 + lane];
            asc = __builtin_amdgcn_mfma_f32_16x16x32_bf16(a, b, asc, 0, 0, 0);
        }
        #pragma unroll
        for (int g = 0; g < 6; ++g) {
            bf16x8 a = *(const bf16x8*)&rr0[frow * 192 + ((g * 32 + fg * 8) ^ fsw)];
            bf16x8 b = ((const bf16x8*)l2w0p)[(nt * 6 + g) * 64 + lane];
            acv = __builtin_amdgcn_mfma_f32_16x16x32_bf16(a, b, acv, 0, 0, 0);
        }
        #pragma unroll
        for (int j = 0; j < 4; ++j) {
            const int row = crow0 + j;
            out[(size_t)(p0 + row) * DIM + nt * 16 + ccol] =
                cs_s[row] * asc[j] + sn_s[row] * acv[j];
        }
    }
    // vector part: 12 (m, nt) pairs; wave w -> pairs 3w..3w+2
    #pragma unroll
    for (int q = 0; q < 3; ++q) {
        const int pair = wave * 3 + q;
        const int m = pair >> 2, nt = pair & 3;
        f32x4 asc = {0.f, 0.f, 0.f, 0.f}, acv = {0.f, 0.f, 0.f, 0.f};
        #pragma unroll
        for (int g = 0; g < 2; ++g) {
            bf16x8 a = *(const bf16x8*)&rin1[(m * 16 + frow) * 64 + ((g * 32 + fg * 8) ^ fsw)];
            bf16x8 b = ((const bf16x8*)scw1p)[(nt * 2 + g) * 64 + lane];
            asc = __builtin_amdgcn_mfma_f32_16x16x32_bf16(a, b, asc, 0, 0, 0);
        }
        #pragma unroll
        for (int g = 0; g < 6; ++g) {
            bf16x8 a = *(const bf16x8*)&rr1[(m * 16 + frow) * 192 + ((g * 32 + fg * 8) ^ fsw)];
            bf16x8 b = ((const bf16x8*)l2w1p)[(nt * 6 + g) * 64 + lane];
            acv = __builtin_amdgcn_mfma_f32_16x16x32_bf16(a, b, acv, 0, 0, 0);
        }
        #pragma unroll
        for (int j = 0; j < 4; ++j) {
            const int row = crow0 + j;
            const int v = nt * 16 + ccol;
            out[(size_t)(p0 + row) * DIM + MUL0 + 3 * v + m] =
                cs_s[row] * asc[j] + sn_s[row] * acv[j];
        }
    }
}

// ---------------------------------------------------------------------------
extern "C" void kernel_launch(void* const* d_in, const int* in_sizes, int n_in,
                              void* d_out, int out_size, void* d_ws, size_t ws_size,
                              hipStream_t stream)
{
    const float* sender_input   = (const float*)d_in[0];
    const float* sender_attr    = (const float*)d_in[1];
    const float* receiver_input = (const float*)d_in[2];
    const float* receiver_attr  = (const float*)d_in[3];
    const int*   edge_src       = (const int*)  d_in[4];
    const int*   edge_dst       = (const int*)  d_in[5];
    const float* edge_attr      = (const float*)d_in[6];
    const float* edge_scalars   = (const float*)d_in[7];
    const float* fc_w1          = (const float*)d_in[8];
    const float* fc_w2          = (const float*)d_in[9];
    const float* lin1_w0        = (const float*)d_in[10];
    const float* lin1_w1        = (const float*)d_in[11];
    const float* sc_w0          = (const float*)d_in[12];
    const float* sc_w1          = (const float*)d_in[13];
    const float* lin2_w0        = (const float*)d_in[14];
    const float* lin2_w1        = (const float*)d_in[15];
    const float* lin3_w         = (const float*)d_in[16];
    float* out = (float*)d_out;

    // ws layout (~2.5 MB): s0h | s1h | w2p | scw0p | l2w0p | scw1p | l2w1p |
    // counts | head | sorted
    __hip_bfloat16* s0h = (__hip_bfloat16*)d_ws;
    __hip_bfloat16* s1h = s0h + (size_t)A_N * MUL0;
    __bf16* w2p   = (__bf16*)(s1h + (size_t)A_N * 192);
    __bf16* scw0p = w2p   + 24 * 4 * 64 * 8;   // 49152
    __bf16* l2w0p = scw0p +  8 * 4 * 64 * 8;   // 16384
    __bf16* scw1p = l2w0p +  8 * 6 * 64 * 8;   // 24576
    __bf16* l2w1p = scw1p +  4 * 2 * 64 * 8;   // 4096
    int* counts = (int*)(l2w1p + 4 * 6 * 64 * 8);
    int* head   = counts + P_N;
    int* sorted = head + P_N;

    sender_kernel<<<A_N, 320, 0, stream>>>(sender_input, sender_attr,
                                           lin1_w0, lin1_w1, s0h, s1h);
    // B-fragment packs (scales folded)
    pack_kernel<<<24, 256, 0, stream>>>(fc_w2,   w2p,   FC_HID, 4, WNUM, RS100);
    pack_kernel<<< 8, 256, 0, stream>>>(sc_w0,   scw0p, 128,    4, 128,  RS128);
    pack_kernel<<<12, 256, 0, stream>>>(lin2_w0, l2w0p, 192,    6, 128,  RS192);
    pack_kernel<<< 2, 256, 0, stream>>>(sc_w1,   scw1p, 64,     2, 64,   RS64);
    pack_kernel<<< 6, 256, 0, stream>>>(lin2_w1, l2w1p, 192,    6, 64,   RS192);

    hipMemsetAsync(counts, 0, P_N * sizeof(int), stream);
    hist_kernel<<<(E_N + 255) / 256, 256, 0, stream>>>(edge_dst, counts);
    scan_kernel<<<1, 1024, 0, stream>>>(counts, head);
    scatter_kernel<<<(E_N + 255) / 256, 256, 0, stream>>>(edge_dst, head, sorted);

    fused_kernel<<<P_N / RT, 256, 0, stream>>>(
        sorted, head, counts, edge_src, edge_attr, edge_scalars,
        fc_w1, w2p, scw0p, scw1p, l2w0p, l2w1p, s0h, s1h,
        receiver_input, receiver_attr, lin3_w, out);
}

// Round 8
// 313.176 us; speedup vs baseline: 2.2590x; 2.2590x over previous
//
#include <hip/hip_runtime.h>
#include <hip/hip_bf16.h>
#include <math.h>

// Problem constants
#define A_N    2000
#define P_N    20000
#define E_N    200000
#define MUL0   128
#define MUL1   64
#define DIM    320     // MUL0 + 3*MUL1
#define NBASIS 10
#define FC_HID 100
#define WNUM   384     // 128+128+64+64
#define MID0   192     // MUL0 + MUL1
#define RDIM   768
#define OV     128     // > max edges per receiver (Poisson(10), max ~30)

// scales
#define RS10   0.31622776601683794f
#define RS100  0.1f
#define RS128  0.08838834764831845f
#define RS64   0.125f
#define RS192  0.07216878364870323f
#define RS3    0.5773502691896258f
#define RSNEI  0.31622776601683794f

typedef __bf16 bf16x8 __attribute__((ext_vector_type(8)));
typedef float  f32x4  __attribute__((ext_vector_type(4)));

__device__ __forceinline__ float bflo(unsigned u) { return __uint_as_float(u << 16); }
__device__ __forceinline__ float bfhi(unsigned u) { return __uint_as_float(u & 0xffff0000u); }

// ---------------------------------------------------------------------------
// Kernel 1: sender transform -> lane-blocked s_pack[a][64][6] bf16:
// slots (g0a, g0b, g1x, g1y, g1z, pad). Same values as proven s0h/s1h.
// ---------------------------------------------------------------------------
__global__ __launch_bounds__(320) void sender_kernel(
    const float* __restrict__ sender_input, const float* __restrict__ sender_attr,
    const float* __restrict__ lin1_w0, const float* __restrict__ lin1_w1,
    __bf16* __restrict__ s_pack)
{
    __shared__ float sin_s[DIM];
    const int a = blockIdx.x;
    const int t = threadIdx.x;
    const float attr = sender_attr[a];
    sin_s[t] = sender_input[(size_t)a * DIM + t] * attr;
    __syncthreads();
    __bf16* row = s_pack + (size_t)a * 384;
    if (t < MUL0) {
        float acc = 0.f;
        for (int u = 0; u < MUL0; ++u)
            acc = fmaf(sin_s[u], lin1_w0[u * MUL0 + t], acc);
        row[(t & 63) * 6 + (t >> 6)] = (__bf16)(acc * RS128);   // slot 0 or 1
    } else {
        const int idx = t - MUL0;          // 0..191 -> (v, m)
        const int v = idx / 3, m = idx - 3 * v;
        float acc = 0.f;
        for (int u = 0; u < MUL1; ++u)
            acc = fmaf(sin_s[MUL0 + 3 * u + m], lin1_w1[u * MUL1 + v], acc);
        row[v * 6 + 2 + m] = (__bf16)(acc * RS64);              // slots 2..4
    }
    if (t < 64) row[t * 6 + 5] = (__bf16)0.f;                   // pad slot
}

// ---------------------------------------------------------------------------
// CSR build: histogram -> scan -> scatter (+ permuted src/attr)
// ---------------------------------------------------------------------------
__global__ __launch_bounds__(256) void hist_kernel(
    const int* __restrict__ edge_dst, int* __restrict__ counts)
{
    const int e = blockIdx.x * 256 + threadIdx.x;
    if (e < E_N) atomicAdd(&counts[edge_dst[e]], 1);
}

__global__ __launch_bounds__(1024) void scan_kernel(
    const int* __restrict__ counts, int* __restrict__ head)
{
    __shared__ int part[1024];
    const int t = threadIdx.x;
    const int base = t * 20;
    int c[20];
    int s = 0;
    #pragma unroll
    for (int i = 0; i < 20; ++i) {
        const int p = base + i;
        c[i] = (p < P_N) ? counts[p] : 0;
        s += c[i];
    }
    part[t] = s;
    __syncthreads();
    for (int off = 1; off < 1024; off <<= 1) {
        const int v = (t >= off) ? part[t - off] : 0;
        __syncthreads();
        part[t] += v;
        __syncthreads();
    }
    int run = (t > 0) ? part[t - 1] : 0;
    #pragma unroll
    for (int i = 0; i < 20; ++i) {
        const int p = base + i;
        if (p < P_N) { head[p] = run; run += c[i]; }
    }
}

__global__ __launch_bounds__(256) void scatter_kernel(
    const int* __restrict__ edge_dst, const int* __restrict__ edge_src,
    const float4* __restrict__ edge_attr4,
    int* __restrict__ head, int* __restrict__ sorted,
    int* __restrict__ src_sorted, float4* __restrict__ attr_sorted)
{
    const int e = blockIdx.x * 256 + threadIdx.x;
    if (e < E_N) {
        const int pos = atomicAdd(&head[edge_dst[e]], 1);
        sorted[pos]      = e;
        src_sorted[pos]  = edge_src[e];
        attr_sorted[pos] = edge_attr4[e];
    }
}

// ---------------------------------------------------------------------------
// pack_w2: fc_w2 -> bf16 MFMA B-fragment order (proven R6). RS100 folded.
// ---------------------------------------------------------------------------
__global__ __launch_bounds__(256) void pack_w2_kernel(
    const float* __restrict__ fc_w2, __bf16* __restrict__ w2p)
{
    const int tid  = blockIdx.x * 256 + threadIdx.x;   // 0..6143
    const int lane = tid & 63;
    const int g    = (tid >> 6) & 3;
    const int n    = tid >> 8;
    const int col  = n * 16 + (lane & 15);
    const int kb   = g * 32 + 8 * (lane >> 4);
    bf16x8 v;
    #pragma unroll
    for (int i = 0; i < 8; ++i) {
        const int k = kb + i;
        v[i] = (__bf16)((k < FC_HID) ? fc_w2[k * WNUM + col] * RS100 : 0.f);
    }
    ((bf16x8*)w2p)[tid] = v;
}

// ---------------------------------------------------------------------------
// Kernel A (MFMA, proven R6 body): MLP + weight GEMM over one chunk.
// Only change vs R6: position clamp (grid may round up) and the C-store goes
// to the lane-blocked layout wbuf[pos][lane][6] (logical col L -> lane L&63,
// slot L>>6).
// ---------------------------------------------------------------------------
__global__ __launch_bounds__(256) void mlp_gemm_chunk_kernel(
    const int* __restrict__ sorted,
    const float* __restrict__ edge_scalars,
    const float* __restrict__ fc_w1, const __bf16* __restrict__ w2p,
    __bf16* __restrict__ wbuf, int cLo)
{
    __shared__ float  fc1s[NBASIS * FC_HID];   // 4 KB
    __shared__ float  es_s[64][NBASIS];        // 2.5 KB
    __shared__ __bf16 h_lds[64 * 128];         // 16 KB
    __shared__ int    eid_s[64];

    const int tid   = threadIdx.x;
    const int wave  = tid >> 6;
    const int lane  = tid & 63;
    const int pbase = blockIdx.x * 64;

    if (tid < 64) {
        int gi = cLo + pbase + tid;
        if (gi >= E_N) gi = E_N - 1;           // pad rows never read
        eid_s[tid] = sorted[gi];
    }
    for (int i = tid; i < NBASIS * FC_HID; i += 256) fc1s[i] = fc_w1[i];
    __syncthreads();

    for (int f = tid; f < 64 * NBASIS; f += 256) {
        const int e = f / NBASIS, i = f - e * NBASIS;
        es_s[e][i] = edge_scalars[(size_t)eid_s[e] * NBASIS + i];
    }
    __syncthreads();

    // h: thread t -> edge t>>2, k-range (t&3)*32..+31; silu; bf16 -> LDS
    {
        const int e  = tid >> 2;
        const int k0 = (tid & 3) * 32;
        float es[NBASIS];
        #pragma unroll
        for (int i = 0; i < NBASIS; ++i) es[i] = es_s[e][i];
        #pragma unroll
        for (int o = 0; o < 4; ++o) {
            bf16x8 hv;
            #pragma unroll
            for (int j = 0; j < 8; ++j) {
                const int k = k0 + o * 8 + j;
                float x = 0.f;
                if (k < FC_HID) {
                    #pragma unroll
                    for (int i = 0; i < NBASIS; ++i)
                        x = fmaf(es[i], fc1s[i * FC_HID + k], x);
                    x *= RS10;
                    x = x / (1.f + __expf(-x));
                }
                hv[j] = (__bf16)x;
            }
            const int idx = (e * 128 + k0 + o * 8) ^ ((e & 7) << 3);
            *(bf16x8*)&h_lds[idx] = hv;
        }
    }
    __syncthreads();

    // A frags (proven R6 layout)
    bf16x8 a[4][4];
    const int arow = lane & 15, ag = lane >> 4;
    #pragma unroll
    for (int mt = 0; mt < 4; ++mt) {
        const int e = mt * 16 + arow;
        #pragma unroll
        for (int g = 0; g < 4; ++g) {
            const int idx = (e * 128 + g * 32 + ag * 8) ^ ((e & 7) << 3);
            a[mt][g] = *(const bf16x8*)&h_lds[idx];
        }
    }

    const bf16x8* w2v = (const bf16x8*)w2p;
    const int row0 = 4 * (lane >> 4), col16 = lane & 15;

    for (int nt = 0; nt < 6; ++nt) {
        const int ntile = wave * 6 + nt;
        bf16x8 b[4];
        #pragma unroll
        for (int g = 0; g < 4; ++g)
            b[g] = w2v[(ntile * 4 + g) * 64 + lane];
        const int L = ntile * 16 + col16;          // logical output column
        #pragma unroll
        for (int mt = 0; mt < 4; ++mt) {
            f32x4 acc = {0.f, 0.f, 0.f, 0.f};
            #pragma unroll
            for (int g = 0; g < 4; ++g)
                acc = __builtin_amdgcn_mfma_f32_16x16x32_bf16(a[mt][g], b[g],
                                                              acc, 0, 0, 0);
            __bf16* wr = &wbuf[(size_t)(pbase + mt * 16 + row0) * 384
                               + (L & 63) * 6 + (L >> 6)];
            #pragma unroll
            for (int j = 0; j < 4; ++j)
                wr[(size_t)j * 384] = (__bf16)acc[j];
        }
    }
}

// ---------------------------------------------------------------------------
// Kernel B: gather + receiver finish (proven R6 structure; consume loop now
// reads lane-blocked wbuf/s_pack as 3 dwords each + permuted src/attr).
// ---------------------------------------------------------------------------
__global__ __launch_bounds__(256) void recv_gather_kernel(
    const int* __restrict__ head, const int* __restrict__ counts,
    const int* __restrict__ src_sorted, const float4* __restrict__ attr_sorted,
    const __bf16* __restrict__ wbuf, const __bf16* __restrict__ s_pack,
    const float* __restrict__ receiver_input, const float* __restrict__ receiver_attr,
    const float* __restrict__ sc_w0,  const float* __restrict__ sc_w1,
    const float* __restrict__ lin2_w0, const float* __restrict__ lin2_w1,
    const float* __restrict__ lin3_w,
    float* __restrict__ out, int cLo, int cHi)
{
    __shared__ float rr_s[4][RDIM];    // 12 KB
    __shared__ float rin_s[4][DIM];    // 5 KB
    __shared__ float cs_s[4], sn_s[4];
    __shared__ int   sel_s[4];

    const int tid  = threadIdx.x;
    const int wave = tid >> 6;
    const int lane = tid & 63;
    const int p = blockIdx.x * 4 + wave;

    const int cnt   = counts[p];
    const int start = head[p] - cnt;               // head = segment end
    const int sel   = (start >= cLo) & (start < cHi);

    if (lane == 0) sel_s[wave] = sel;
    __syncthreads();
    if ((sel_s[0] | sel_s[1] | sel_s[2] | sel_s[3]) == 0) return;  // uniform

    const int cntEff = sel ? cnt : 0;

    float acc[12];
    #pragma unroll
    for (int i = 0; i < 12; ++i) acc[i] = 0.f;

    #pragma unroll 2
    for (int i = 0; i < cntEff; ++i) {
        const int pos = start + i;
        const unsigned* wq = (const unsigned*)((const char*)wbuf
                             + (size_t)(pos - cLo) * 768 + lane * 12);
        const int    src = src_sorted[pos];
        const float4 ea  = attr_sorted[pos];
        const unsigned* sq = (const unsigned*)((const char*)s_pack
                             + (size_t)src * 768 + lane * 12);
        const unsigned w01 = wq[0], w23 = wq[1], w45 = wq[2];
        const unsigned s01 = sq[0], s23 = sq[1], s45 = sq[2];

        const float sh0 = ea.x, sh1x = ea.y, sh1y = ea.z, sh1z = ea.w;
        const float w0a = bflo(w01), w0b = bfhi(w01);
        const float w1a = bflo(w23), w1b = bfhi(w23);
        const float w2v = bflo(w45), w3v = bfhi(w45);
        const float g0a = bflo(s01), g0b = bfhi(s01);
        const float g1x = bflo(s23), g1y = bfhi(s23), g1z = bflo(s45);

        acc[0] = fmaf(w0a * g0a, sh0, acc[0]);
        acc[1] = fmaf(w0b * g0b, sh0, acc[1]);
        const float dotg = fmaf(g1x, sh1x, fmaf(g1y, sh1y, g1z * sh1z)) * RS3;
        acc[2] = fmaf(w3v, dotg, acc[2]);
        const float p1a = w1a * g0a, p1b = w1b * g0b;
        acc[3] = fmaf(p1a, sh1x, acc[3]);
        acc[4] = fmaf(p1a, sh1y, acc[4]);
        acc[5] = fmaf(p1a, sh1z, acc[5]);
        acc[6] = fmaf(p1b, sh1x, acc[6]);
        acc[7] = fmaf(p1b, sh1y, acc[7]);
        acc[8] = fmaf(p1b, sh1z, acc[8]);
        const float q = w2v * sh0;
        acc[9]  = fmaf(q, g1x, acc[9]);
        acc[10] = fmaf(q, g1y, acc[10]);
        acc[11] = fmaf(q, g1z, acc[11]);
    }

    // stage scaled r row + scaled receiver_input into LDS (proven R4-R6)
    const float rattr = receiver_attr[p];
    const float rfac  = RSNEI * rattr;
    rr_s[wave][lane]               = acc[0]  * rfac;
    rr_s[wave][64 + lane]          = acc[1]  * rfac;
    rr_s[wave][128 + lane]         = acc[2]  * rfac;
    rr_s[wave][192 + 3 * lane]     = acc[3]  * rfac;
    rr_s[wave][192 + 3 * lane + 1] = acc[4]  * rfac;
    rr_s[wave][192 + 3 * lane + 2] = acc[5]  * rfac;
    rr_s[wave][384 + 3 * lane]     = acc[6]  * rfac;
    rr_s[wave][384 + 3 * lane + 1] = acc[7]  * rfac;
    rr_s[wave][384 + 3 * lane + 2] = acc[8]  * rfac;
    rr_s[wave][576 + 3 * lane]     = acc[9]  * rfac;
    rr_s[wave][576 + 3 * lane + 1] = acc[10] * rfac;
    rr_s[wave][576 + 3 * lane + 2] = acc[11] * rfac;
    for (int jj = lane; jj < DIM; jj += 64)
        rin_s[wave][jj] = receiver_input[(size_t)p * DIM + jj] * rattr;
    __syncthreads();

    // angle per receiver
    if (tid < 32) {
        const int pw = tid >> 3, i0 = tid & 7;
        float a = 0.f;
        for (int u = i0; u < MID0; u += 8)
            a = fmaf(rr_s[pw][u], lin3_w[u], a);
        a += __shfl_xor(a, 1);
        a += __shfl_xor(a, 2);
        a += __shfl_xor(a, 4);
        if (i0 == 0) {
            a *= 0.1f * RS192;
            cs_s[pw] = __cosf(a);
            sn_s[pw] = __sinf(a);
        }
    }
    __syncthreads();

    // output transform (proven R4-R6)
    for (int jj = tid; jj < DIM; jj += 256) {
        float asc[4] = {0.f, 0.f, 0.f, 0.f};
        float acv[4] = {0.f, 0.f, 0.f, 0.f};
        if (jj < MUL0) {
            for (int u = 0; u < MUL0; ++u) {
                const float w = sc_w0[u * MUL0 + jj];
                #pragma unroll
                for (int pp = 0; pp < 4; ++pp)
                    asc[pp] = fmaf(rin_s[pp][u], w, asc[pp]);
            }
            for (int u = 0; u < MID0; ++u) {
                const float w = lin2_w0[u * MUL0 + jj];
                #pragma unroll
                for (int pp = 0; pp < 4; ++pp)
                    acv[pp] = fmaf(rr_s[pp][u], w, acv[pp]);
            }
            #pragma unroll
            for (int pp = 0; pp < 4; ++pp)
                if (sel_s[pp])
                    out[(size_t)(blockIdx.x * 4 + pp) * DIM + jj] =
                        cs_s[pp] * asc[pp] * RS128 + sn_s[pp] * acv[pp] * RS192;
        } else {
            const int idx = jj - MUL0;
            const int v = idx / 3, m = idx - 3 * v;
            for (int u = 0; u < MUL1; ++u) {
                const float w = sc_w1[u * MUL1 + v];
                #pragma unroll
                for (int pp = 0; pp < 4; ++pp)
                    asc[pp] = fmaf(rin_s[pp][MUL0 + 3 * u + m], w, asc[pp]);
            }
            for (int u = 0; u < MID0; ++u) {
                const float w = lin2_w1[u * MUL1 + v];
                #pragma unroll
                for (int pp = 0; pp < 4; ++pp)
                    acv[pp] = fmaf(rr_s[pp][192 + 3 * u + m], w, acv[pp]);
            }
            #pragma unroll
            for (int pp = 0; pp < 4; ++pp)
                if (sel_s[pp])
                    out[(size_t)(blockIdx.x * 4 + pp) * DIM + jj] =
                        cs_s[pp] * asc[pp] * RS64 + sn_s[pp] * acv[pp] * RS192;
        }
    }
}

// ---------------------------------------------------------------------------
extern "C" void kernel_launch(void* const* d_in, const int* in_sizes, int n_in,
                              void* d_out, int out_size, void* d_ws, size_t ws_size,
                              hipStream_t stream)
{
    const float* sender_input   = (const float*)d_in[0];
    const float* sender_attr    = (const float*)d_in[1];
    const float* receiver_input = (const float*)d_in[2];
    const float* receiver_attr  = (const float*)d_in[3];
    const int*   edge_src       = (const int*)  d_in[4];
    const int*   edge_dst       = (const int*)  d_in[5];
    const float* edge_attr      = (const float*)d_in[6];
    const float* edge_scalars   = (const float*)d_in[7];
    const float* fc_w1          = (const float*)d_in[8];
    const float* fc_w2          = (const float*)d_in[9];
    const float* lin1_w0        = (const float*)d_in[10];
    const float* lin1_w1        = (const float*)d_in[11];
    const float* sc_w0          = (const float*)d_in[12];
    const float* sc_w1          = (const float*)d_in[13];
    const float* lin2_w0        = (const float*)d_in[14];
    const float* lin2_w1        = (const float*)d_in[15];
    const float* lin3_w         = (const float*)d_in[16];
    float* out = (float*)d_out;

    // ws layout: fixed arrays first, wbuf takes the remainder.
    // attr_sorted [E] f4 | s_pack [A*384] bf16 | w2p | counts | head |
    // sorted [E] | src_sorted [E] | wbuf [cchunk+OV+64][384] bf16
    char* wsb = (char*)d_ws;
    float4* attr_sorted = (float4*)wsb;                                  // 3.20 MB
    __bf16* s_pack = (__bf16*)(wsb + (size_t)E_N * 16);                  // 1.54 MB
    __bf16* w2p    = s_pack + (size_t)A_N * 384;                         // 96 KB
    int* counts     = (int*)(w2p + 24 * 4 * 64 * 8);
    int* head       = counts + P_N;
    int* sorted     = head + P_N;
    int* src_sorted = sorted + E_N;
    __bf16* wbuf    = (__bf16*)(src_sorted + E_N);
    const size_t fixedB = (size_t)((char*)wbuf - wsb);                   // ~6.59 MB

    // dynamic chunk size from available workspace (>=64MB proven -> 3 chunks)
    long long maxpos = (long long)((ws_size - fixedB) / 768);
    long long cc = (maxpos - OV - 64) & ~63LL;
    int cchunk = (cc > E_N) ? E_N : (int)cc;

    sender_kernel<<<A_N, 320, 0, stream>>>(sender_input, sender_attr,
                                           lin1_w0, lin1_w1, s_pack);
    pack_w2_kernel<<<24, 256, 0, stream>>>(fc_w2, w2p);
    hipMemsetAsync(counts, 0, P_N * sizeof(int), stream);
    hist_kernel<<<(E_N + 255) / 256, 256, 0, stream>>>(edge_dst, counts);
    scan_kernel<<<1, 1024, 0, stream>>>(counts, head);
    scatter_kernel<<<(E_N + 255) / 256, 256, 0, stream>>>(
        edge_dst, edge_src, (const float4*)edge_attr,
        head, sorted, src_sorted, attr_sorted);

    for (int cLo = 0; cLo < E_N; cLo += cchunk) {
        int nPos = E_N - cLo;
        if (nPos > cchunk + OV) nPos = cchunk + OV;
        const int cHi = (cLo + cchunk >= E_N) ? (E_N + 1) : (cLo + cchunk);
        mlp_gemm_chunk_kernel<<<(nPos + 63) / 64, 256, 0, stream>>>(
            sorted, edge_scalars, fc_w1, w2p, wbuf, cLo);
        recv_gather_kernel<<<P_N / 4, 256, 0, stream>>>(
            head, counts, src_sorted, attr_sorted, wbuf, s_pack,
            receiver_input, receiver_attr, sc_w0, sc_w1, lin2_w0, lin2_w1,
            lin3_w, out, cLo, cHi);
    }
}

// Round 9
// 273.181 us; speedup vs baseline: 2.5897x; 1.1464x over previous
//
#include <hip/hip_runtime.h>
#include <hip/hip_bf16.h>
#include <math.h>

// Problem constants
#define A_N    2000
#define P_N    20000
#define PPAD   20032   // P_N padded to 64 rows (out_transform tail)
#define E_N    200000
#define MUL0   128
#define MUL1   64
#define DIM    320     // MUL0 + 3*MUL1
#define NBASIS 10
#define FC_HID 100
#define WNUM   384     // 128+128+64+64
#define MID0   192     // MUL0 + MUL1
#define OV     128     // > max edges per receiver (Poisson(10), max ~30)

// scales
#define RS10   0.31622776601683794f
#define RS100  0.1f
#define RS128  0.08838834764831845f
#define RS64   0.125f
#define RS192  0.07216878364870323f
#define RS3    0.5773502691896258f
#define RSNEI  0.31622776601683794f

typedef __bf16 bf16x8 __attribute__((ext_vector_type(8)));
typedef float  f32x4  __attribute__((ext_vector_type(4)));

__device__ __forceinline__ float bflo(unsigned u) { return __uint_as_float(u << 16); }
__device__ __forceinline__ float bfhi(unsigned u) { return __uint_as_float(u & 0xffff0000u); }

// ---------------------------------------------------------------------------
// Kernel 1: sender transform -> lane-blocked s_pack[a][64][6] bf16 (proven R8)
// ---------------------------------------------------------------------------
__global__ __launch_bounds__(320) void sender_kernel(
    const float* __restrict__ sender_input, const float* __restrict__ sender_attr,
    const float* __restrict__ lin1_w0, const float* __restrict__ lin1_w1,
    __bf16* __restrict__ s_pack)
{
    __shared__ float sin_s[DIM];
    const int a = blockIdx.x;
    const int t = threadIdx.x;
    const float attr = sender_attr[a];
    sin_s[t] = sender_input[(size_t)a * DIM + t] * attr;
    __syncthreads();
    __bf16* row = s_pack + (size_t)a * 384;
    if (t < MUL0) {
        float acc = 0.f;
        for (int u = 0; u < MUL0; ++u)
            acc = fmaf(sin_s[u], lin1_w0[u * MUL0 + t], acc);
        row[(t & 63) * 6 + (t >> 6)] = (__bf16)(acc * RS128);
    } else {
        const int idx = t - MUL0;
        const int v = idx / 3, m = idx - 3 * v;
        float acc = 0.f;
        for (int u = 0; u < MUL1; ++u)
            acc = fmaf(sin_s[MUL0 + 3 * u + m], lin1_w1[u * MUL1 + v], acc);
        row[v * 6 + 2 + m] = (__bf16)(acc * RS64);
    }
    if (t < 64) row[t * 6 + 5] = (__bf16)0.f;
}

// ---------------------------------------------------------------------------
// CSR build: histogram -> scan -> scatter (+ permuted src/attr) (proven R8)
// ---------------------------------------------------------------------------
__global__ __launch_bounds__(256) void hist_kernel(
    const int* __restrict__ edge_dst, int* __restrict__ counts)
{
    const int e = blockIdx.x * 256 + threadIdx.x;
    if (e < E_N) atomicAdd(&counts[edge_dst[e]], 1);
}

__global__ __launch_bounds__(1024) void scan_kernel(
    const int* __restrict__ counts, int* __restrict__ head)
{
    __shared__ int part[1024];
    const int t = threadIdx.x;
    const int base = t * 20;
    int c[20];
    int s = 0;
    #pragma unroll
    for (int i = 0; i < 20; ++i) {
        const int p = base + i;
        c[i] = (p < P_N) ? counts[p] : 0;
        s += c[i];
    }
    part[t] = s;
    __syncthreads();
    for (int off = 1; off < 1024; off <<= 1) {
        const int v = (t >= off) ? part[t - off] : 0;
        __syncthreads();
        part[t] += v;
        __syncthreads();
    }
    int run = (t > 0) ? part[t - 1] : 0;
    #pragma unroll
    for (int i = 0; i < 20; ++i) {
        const int p = base + i;
        if (p < P_N) { head[p] = run; run += c[i]; }
    }
}

__global__ __launch_bounds__(256) void scatter_kernel(
    const int* __restrict__ edge_dst, const int* __restrict__ edge_src,
    const float4* __restrict__ edge_attr4,
    int* __restrict__ head, int* __restrict__ sorted,
    int* __restrict__ src_sorted, float4* __restrict__ attr_sorted)
{
    const int e = blockIdx.x * 256 + threadIdx.x;
    if (e < E_N) {
        const int pos = atomicAdd(&head[edge_dst[e]], 1);
        sorted[pos]      = e;
        src_sorted[pos]  = edge_src[e];
        attr_sorted[pos] = edge_attr4[e];
    }
}

// ---------------------------------------------------------------------------
// pack_w2: fc_w2 -> bf16 MFMA B-fragment order (proven R6-R8). RS100 folded.
// ---------------------------------------------------------------------------
__global__ __launch_bounds__(256) void pack_w2_kernel(
    const float* __restrict__ fc_w2, __bf16* __restrict__ w2p)
{
    const int tid  = blockIdx.x * 256 + threadIdx.x;
    const int lane = tid & 63;
    const int g    = (tid >> 6) & 3;
    const int n    = tid >> 8;
    const int col  = n * 16 + (lane & 15);
    const int kb   = g * 32 + 8 * (lane >> 4);
    bf16x8 v;
    #pragma unroll
    for (int i = 0; i < 8; ++i) {
        const int k = kb + i;
        v[i] = (__bf16)((k < FC_HID) ? fc_w2[k * WNUM + col] * RS100 : 0.f);
    }
    ((bf16x8*)w2p)[tid] = v;
}

// ---------------------------------------------------------------------------
// Generic pack (proven R7): src [K][N] f32 -> bf16 B-fragment order,
// frag fi = n*KG + g; lane l elem i: k = g*32+8*(l>>4)+i, col = n*16+(l&15).
// ---------------------------------------------------------------------------
__global__ __launch_bounds__(256) void pack_kernel(
    const float* __restrict__ src, __bf16* __restrict__ dst,
    int K, int KG, int N, float scale)
{
    const int tid  = blockIdx.x * 256 + threadIdx.x;
    const int lane = tid & 63;
    const int fi   = tid >> 6;
    const int g    = fi % KG;
    const int n    = fi / KG;
    const int col  = n * 16 + (lane & 15);
    const int kb   = g * 32 + 8 * (lane >> 4);
    bf16x8 v;
    #pragma unroll
    for (int i = 0; i < 8; ++i) {
        const int k = kb + i;
        v[i] = (__bf16)((k < K) ? src[(size_t)k * N + col] * scale : 0.f);
    }
    ((bf16x8*)dst)[tid] = v;
}

// ---------------------------------------------------------------------------
// Kernel A (proven R8): MLP + weight MFMA-GEMM over one chunk; lane-blocked
// wbuf[pos][lane][6] C-store.
// ---------------------------------------------------------------------------
__global__ __launch_bounds__(256) void mlp_gemm_chunk_kernel(
    const int* __restrict__ sorted,
    const float* __restrict__ edge_scalars,
    const float* __restrict__ fc_w1, const __bf16* __restrict__ w2p,
    __bf16* __restrict__ wbuf, int cLo)
{
    __shared__ float  fc1s[NBASIS * FC_HID];
    __shared__ float  es_s[64][NBASIS];
    __shared__ __bf16 h_lds[64 * 128];
    __shared__ int    eid_s[64];

    const int tid   = threadIdx.x;
    const int wave  = tid >> 6;
    const int lane  = tid & 63;
    const int pbase = blockIdx.x * 64;

    if (tid < 64) {
        int gi = cLo + pbase + tid;
        if (gi >= E_N) gi = E_N - 1;
        eid_s[tid] = sorted[gi];
    }
    for (int i = tid; i < NBASIS * FC_HID; i += 256) fc1s[i] = fc_w1[i];
    __syncthreads();

    for (int f = tid; f < 64 * NBASIS; f += 256) {
        const int e = f / NBASIS, i = f - e * NBASIS;
        es_s[e][i] = edge_scalars[(size_t)eid_s[e] * NBASIS + i];
    }
    __syncthreads();

    {
        const int e  = tid >> 2;
        const int k0 = (tid & 3) * 32;
        float es[NBASIS];
        #pragma unroll
        for (int i = 0; i < NBASIS; ++i) es[i] = es_s[e][i];
        #pragma unroll
        for (int o = 0; o < 4; ++o) {
            bf16x8 hv;
            #pragma unroll
            for (int j = 0; j < 8; ++j) {
                const int k = k0 + o * 8 + j;
                float x = 0.f;
                if (k < FC_HID) {
                    #pragma unroll
                    for (int i = 0; i < NBASIS; ++i)
                        x = fmaf(es[i], fc1s[i * FC_HID + k], x);
                    x *= RS10;
                    x = x / (1.f + __expf(-x));
                }
                hv[j] = (__bf16)x;
            }
            const int idx = (e * 128 + k0 + o * 8) ^ ((e & 7) << 3);
            *(bf16x8*)&h_lds[idx] = hv;
        }
    }
    __syncthreads();

    bf16x8 a[4][4];
    const int arow = lane & 15, ag = lane >> 4;
    #pragma unroll
    for (int mt = 0; mt < 4; ++mt) {
        const int e = mt * 16 + arow;
        #pragma unroll
        for (int g = 0; g < 4; ++g) {
            const int idx = (e * 128 + g * 32 + ag * 8) ^ ((e & 7) << 3);
            a[mt][g] = *(const bf16x8*)&h_lds[idx];
        }
    }

    const bf16x8* w2v = (const bf16x8*)w2p;
    const int row0 = 4 * (lane >> 4), col16 = lane & 15;

    for (int nt = 0; nt < 6; ++nt) {
        const int ntile = wave * 6 + nt;
        bf16x8 b[4];
        #pragma unroll
        for (int g = 0; g < 4; ++g)
            b[g] = w2v[(ntile * 4 + g) * 64 + lane];
        const int L = ntile * 16 + col16;
        #pragma unroll
        for (int mt = 0; mt < 4; ++mt) {
            f32x4 acc = {0.f, 0.f, 0.f, 0.f};
            #pragma unroll
            for (int g = 0; g < 4; ++g)
                acc = __builtin_amdgcn_mfma_f32_16x16x32_bf16(a[mt][g], b[g],
                                                              acc, 0, 0, 0);
            __bf16* wr = &wbuf[(size_t)(pbase + mt * 16 + row0) * 384
                               + (L & 63) * 6 + (L >> 6)];
            #pragma unroll
            for (int j = 0; j < 4; ++j)
                wr[(size_t)j * 384] = (__bf16)acc[j];
        }
    }
}

// ---------------------------------------------------------------------------
// Kernel B (slim gather): consume loop (proven R8) -> rbuf/rinp bf16 + angle.
// rbuf layout: [0..191]=r0(U); [192+192m+U]=r1m(U). rinp: [0..127]=cols,
// [128+64m+u]=col(128+3u+m). rfac/rattr folded. No barriers after select.
// ---------------------------------------------------------------------------
__global__ __launch_bounds__(256) void gather_kernel(
    const int* __restrict__ head, const int* __restrict__ counts,
    const int* __restrict__ src_sorted, const float4* __restrict__ attr_sorted,
    const __bf16* __restrict__ wbuf, const __bf16* __restrict__ s_pack,
    const float* __restrict__ receiver_input, const float* __restrict__ receiver_attr,
    const float* __restrict__ lin3_w,
    __bf16* __restrict__ rbuf, __bf16* __restrict__ rinp,
    float* __restrict__ cs_arr, float* __restrict__ sn_arr,
    int cLo, int cHi)
{
    __shared__ int sel_s[4];
    const int tid  = threadIdx.x;
    const int wave = tid >> 6;
    const int lane = tid & 63;
    const int p = blockIdx.x * 4 + wave;

    const int cnt   = counts[p];
    const int start = head[p] - cnt;
    const int sel   = (start >= cLo) & (start < cHi);

    if (lane == 0) sel_s[wave] = sel;
    __syncthreads();
    if ((sel_s[0] | sel_s[1] | sel_s[2] | sel_s[3]) == 0) return;
    if (!sel) return;   // no barriers below -> per-wave exit is safe

    float acc[12];
    #pragma unroll
    for (int i = 0; i < 12; ++i) acc[i] = 0.f;

    #pragma unroll 2
    for (int i = 0; i < cnt; ++i) {
        const int pos = start + i;
        const unsigned* wq = (const unsigned*)((const char*)wbuf
                             + (size_t)(pos - cLo) * 768 + lane * 12);
        const int    src = src_sorted[pos];
        const float4 ea  = attr_sorted[pos];
        const unsigned* sq = (const unsigned*)((const char*)s_pack
                             + (size_t)src * 768 + lane * 12);
        const unsigned w01 = wq[0], w23 = wq[1], w45 = wq[2];
        const unsigned s01 = sq[0], s23 = sq[1], s45 = sq[2];

        const float sh0 = ea.x, sh1x = ea.y, sh1y = ea.z, sh1z = ea.w;
        const float w0a = bflo(w01), w0b = bfhi(w01);
        const float w1a = bflo(w23), w1b = bfhi(w23);
        const float w2v = bflo(w45), w3v = bfhi(w45);
        const float g0a = bflo(s01), g0b = bfhi(s01);
        const float g1x = bflo(s23), g1y = bfhi(s23), g1z = bflo(s45);

        acc[0] = fmaf(w0a * g0a, sh0, acc[0]);
        acc[1] = fmaf(w0b * g0b, sh0, acc[1]);
        const float dotg = fmaf(g1x, sh1x, fmaf(g1y, sh1y, g1z * sh1z)) * RS3;
        acc[2] = fmaf(w3v, dotg, acc[2]);
        const float p1a = w1a * g0a, p1b = w1b * g0b;
        acc[3] = fmaf(p1a, sh1x, acc[3]);
        acc[4] = fmaf(p1a, sh1y, acc[4]);
        acc[5] = fmaf(p1a, sh1z, acc[5]);
        acc[6] = fmaf(p1b, sh1x, acc[6]);
        acc[7] = fmaf(p1b, sh1y, acc[7]);
        acc[8] = fmaf(p1b, sh1z, acc[8]);
        const float q = w2v * sh0;
        acc[9]  = fmaf(q, g1x, acc[9]);
        acc[10] = fmaf(q, g1y, acc[10]);
        acc[11] = fmaf(q, g1z, acc[11]);
    }

    const float rattr = receiver_attr[p];
    const float rfac  = RSNEI * rattr;
    const float v0 = acc[0] * rfac, v1 = acc[1] * rfac, v2 = acc[2] * rfac;

    // angle: per-lane partial over the 192 r0 entries, 64-lane butterfly
    float part = v0 * lin3_w[lane] + v1 * lin3_w[64 + lane] + v2 * lin3_w[128 + lane];
    #pragma unroll
    for (int off = 1; off < 64; off <<= 1) part += __shfl_xor(part, off);
    if (lane == 0) {
        const float a = part * 0.1f * RS192;
        cs_arr[p] = __cosf(a);
        sn_arr[p] = __sinf(a);
    }

    __bf16* rb = rbuf + (size_t)p * 768;
    rb[lane]       = (__bf16)v0;
    rb[64 + lane]  = (__bf16)v1;
    rb[128 + lane] = (__bf16)v2;
    #pragma unroll
    for (int m = 0; m < 3; ++m) {
        __bf16* r1 = rb + 192 + m * 192;
        r1[lane]        = (__bf16)(acc[3 + m] * rfac);
        r1[64 + lane]   = (__bf16)(acc[6 + m] * rfac);
        r1[128 + lane]  = (__bf16)(acc[9 + m] * rfac);
    }

    // rin pack (rattr folded)
    __bf16* rp = rinp + (size_t)p * 320;
    #pragma unroll
    for (int q = 0; q < 5; ++q) {
        const int t = q * 64 + lane;
        const float val = receiver_input[(size_t)p * DIM + t] * rattr;
        int pos;
        if (t < 128) pos = t;
        else { const int idx = t - 128; const int u = idx / 3, m = idx - 3 * u;
               pos = 128 + m * 64 + u; }
        rp[pos] = (__bf16)val;
    }
}

// ---------------------------------------------------------------------------
// Kernel C: output transform, pure MFMA, no LDS/barriers. 16 rows per wave.
// A-frags direct from rbuf/rinp; B-frags from proven R7 packs (scales folded).
// ---------------------------------------------------------------------------
__global__ __launch_bounds__(256) void out_transform_kernel(
    const __bf16* __restrict__ rbuf, const __bf16* __restrict__ rinp,
    const __bf16* __restrict__ scw0p, const __bf16* __restrict__ l2w0p,
    const __bf16* __restrict__ scw1p, const __bf16* __restrict__ l2w1p,
    const float* __restrict__ cs_arr, const float* __restrict__ sn_arr,
    float* __restrict__ out)
{
    const int wave = threadIdx.x >> 6, lane = threadIdx.x & 63;
    const int pw0 = blockIdx.x * 64 + wave * 16;
    const int arow = lane & 15, ag = lane >> 4;
    const int crow0 = 4 * (lane >> 4), ccol = lane & 15;

    const size_t riRow = (size_t)(pw0 + arow) * 320;
    const size_t rbRow = (size_t)(pw0 + arow) * 768;

    float cs[4], sn[4];
    #pragma unroll
    for (int j = 0; j < 4; ++j) {
        cs[j] = cs_arr[pw0 + crow0 + j];
        sn[j] = sn_arr[pw0 + crow0 + j];
    }

    // ---- scalar part: out cols 0..127 ----
    {
        bf16x8 ain[4], arr[6];
        #pragma unroll
        for (int g = 0; g < 4; ++g)
            ain[g] = *(const bf16x8*)&rinp[riRow + g * 32 + ag * 8];
        #pragma unroll
        for (int g = 0; g < 6; ++g)
            arr[g] = *(const bf16x8*)&rbuf[rbRow + g * 32 + ag * 8];
        #pragma unroll
        for (int nt = 0; nt < 8; ++nt) {
            f32x4 asc = {0.f, 0.f, 0.f, 0.f}, acv = {0.f, 0.f, 0.f, 0.f};
            #pragma unroll
            for (int g = 0; g < 4; ++g)
                asc = __builtin_amdgcn_mfma_f32_16x16x32_bf16(
                    ain[g], ((const bf16x8*)scw0p)[(nt * 4 + g) * 64 + lane], asc, 0, 0, 0);
            #pragma unroll
            for (int g = 0; g < 6; ++g)
                acv = __builtin_amdgcn_mfma_f32_16x16x32_bf16(
                    arr[g], ((const bf16x8*)l2w0p)[(nt * 6 + g) * 64 + lane], acv, 0, 0, 0);
            #pragma unroll
            for (int j = 0; j < 4; ++j) {
                const int row = pw0 + crow0 + j;
                if (row < P_N)
                    out[(size_t)row * DIM + nt * 16 + ccol] =
                        cs[j] * asc[j] + sn[j] * acv[j];
            }
        }
    }
    // ---- vector part: out cols 128 + 3v + m ----
    #pragma unroll
    for (int m = 0; m < 3; ++m) {
        bf16x8 ain1[2], arr1[6];
        #pragma unroll
        for (int g = 0; g < 2; ++g)
            ain1[g] = *(const bf16x8*)&rinp[riRow + 128 + m * 64 + g * 32 + ag * 8];
        #pragma unroll
        for (int g = 0; g < 6; ++g)
            arr1[g] = *(const bf16x8*)&rbuf[rbRow + 192 + m * 192 + g * 32 + ag * 8];
        #pragma unroll
        for (int vt = 0; vt < 4; ++vt) {
            f32x4 asc = {0.f, 0.f, 0.f, 0.f}, acv = {0.f, 0.f, 0.f, 0.f};
            #pragma unroll
            for (int g = 0; g < 2; ++g)
                asc = __builtin_amdgcn_mfma_f32_16x16x32_bf16(
                    ain1[g], ((const bf16x8*)scw1p)[(vt * 2 + g) * 64 + lane], asc, 0, 0, 0);
            #pragma unroll
            for (int g = 0; g < 6; ++g)
                acv = __builtin_amdgcn_mfma_f32_16x16x32_bf16(
                    arr1[g], ((const bf16x8*)l2w1p)[(vt * 6 + g) * 64 + lane], acv, 0, 0, 0);
            #pragma unroll
            for (int j = 0; j < 4; ++j) {
                const int row = pw0 + crow0 + j;
                if (row < P_N) {
                    const int v = vt * 16 + ccol;
                    out[(size_t)row * DIM + MUL0 + 3 * v + m] =
                        cs[j] * asc[j] + sn[j] * acv[j];
                }
            }
        }
    }
}

// ---------------------------------------------------------------------------
extern "C" void kernel_launch(void* const* d_in, const int* in_sizes, int n_in,
                              void* d_out, int out_size, void* d_ws, size_t ws_size,
                              hipStream_t stream)
{
    const float* sender_input   = (const float*)d_in[0];
    const float* sender_attr    = (const float*)d_in[1];
    const float* receiver_input = (const float*)d_in[2];
    const float* receiver_attr  = (const float*)d_in[3];
    const int*   edge_src       = (const int*)  d_in[4];
    const int*   edge_dst       = (const int*)  d_in[5];
    const float* edge_attr      = (const float*)d_in[6];
    const float* edge_scalars   = (const float*)d_in[7];
    const float* fc_w1          = (const float*)d_in[8];
    const float* fc_w2          = (const float*)d_in[9];
    const float* lin1_w0        = (const float*)d_in[10];
    const float* lin1_w1        = (const float*)d_in[11];
    const float* sc_w0          = (const float*)d_in[12];
    const float* sc_w1          = (const float*)d_in[13];
    const float* lin2_w0        = (const float*)d_in[14];
    const float* lin2_w1        = (const float*)d_in[15];
    const float* lin3_w         = (const float*)d_in[16];
    float* out = (float*)d_out;

    // ws layout: fixed buffers first, wbuf takes the remainder.
    char* wsb = (char*)d_ws;
    float4* attr_sorted = (float4*)wsb;                                   // 3.20 MB
    __bf16* s_pack = (__bf16*)(wsb + (size_t)E_N * 16);                   // 1.54 MB
    __bf16* w2p    = s_pack + (size_t)A_N * 384;                          // 96 KB
    __bf16* scw0p  = w2p   + 24 * 4 * 64 * 8;
    __bf16* l2w0p  = scw0p +  8 * 4 * 64 * 8;
    __bf16* scw1p  = l2w0p +  8 * 6 * 64 * 8;
    __bf16* l2w1p  = scw1p +  4 * 2 * 64 * 8;
    __bf16* rbuf   = l2w1p +  4 * 6 * 64 * 8;                             // 30.8 MB
    __bf16* rinp   = rbuf + (size_t)PPAD * 768;                           // 12.8 MB
    float*  cs_arr = (float*)(rinp + (size_t)PPAD * 320);
    float*  sn_arr = cs_arr + PPAD;
    int* counts     = (int*)(sn_arr + PPAD);
    int* head       = counts + P_N;
    int* sorted     = head + P_N;
    int* src_sorted = sorted + E_N;
    __bf16* wbuf    = (__bf16*)(src_sorted + E_N);
    const size_t fixedB = (size_t)((char*)wbuf - wsb);                    // ~50.6 MB

    // dynamic chunk size from remaining workspace
    long long maxpos = (long long)((ws_size - fixedB) / 768);
    long long cc = (maxpos - OV - 64) & ~63LL;
    int cchunk = (cc > E_N) ? E_N : (int)cc;

    sender_kernel<<<A_N, 320, 0, stream>>>(sender_input, sender_attr,
                                           lin1_w0, lin1_w1, s_pack);
    pack_w2_kernel<<<24, 256, 0, stream>>>(fc_w2, w2p);
    pack_kernel<<< 8, 256, 0, stream>>>(sc_w0,   scw0p, 128, 4, 128, RS128);
    pack_kernel<<<12, 256, 0, stream>>>(lin2_w0, l2w0p, 192, 6, 128, RS192);
    pack_kernel<<< 2, 256, 0, stream>>>(sc_w1,   scw1p, 64,  2, 64,  RS64);
    pack_kernel<<< 6, 256, 0, stream>>>(lin2_w1, l2w1p, 192, 6, 64,  RS192);

    hipMemsetAsync(counts, 0, P_N * sizeof(int), stream);
    hist_kernel<<<(E_N + 255) / 256, 256, 0, stream>>>(edge_dst, counts);
    scan_kernel<<<1, 1024, 0, stream>>>(counts, head);
    scatter_kernel<<<(E_N + 255) / 256, 256, 0, stream>>>(
        edge_dst, edge_src, (const float4*)edge_attr,
        head, sorted, src_sorted, attr_sorted);

    for (int cLo = 0; cLo < E_N; cLo += cchunk) {
        int nPos = E_N - cLo;
        if (nPos > cchunk + OV) nPos = cchunk + OV;
        const int cHi = (cLo + cchunk >= E_N) ? (E_N + 1) : (cLo + cchunk);
        mlp_gemm_chunk_kernel<<<(nPos + 63) / 64, 256, 0, stream>>>(
            sorted, edge_scalars, fc_w1, w2p, wbuf, cLo);
        gather_kernel<<<P_N / 4, 256, 0, stream>>>(
            head, counts, src_sorted, attr_sorted, wbuf, s_pack,
            receiver_input, receiver_attr, lin3_w,
            rbuf, rinp, cs_arr, sn_arr, cLo, cHi);
    }

    out_transform_kernel<<<(P_N + 63) / 64, 256, 0, stream>>>(
        rbuf, rinp, scw0p, l2w0p, scw1p, l2w1p, cs_arr, sn_arr, out);
}

// Round 10
// 244.991 us; speedup vs baseline: 2.8877x; 1.1151x over previous
//
#include <hip/hip_runtime.h>
#include <hip/hip_bf16.h>
#include <math.h>

// Problem constants
#define A_N    2000
#define P_N    20000
#define PPAD   20032   // P_N padded to 64 rows (out_transform tail)
#define E_N    200000
#define MUL0   128
#define MUL1   64
#define DIM    320     // MUL0 + 3*MUL1
#define NBASIS 10
#define FC_HID 100
#define WNUM   384     // 128+128+64+64
#define MID0   192     // MUL0 + MUL1
#define OV     128     // > max edges per receiver (Poisson(10), max ~30)

// scales
#define RS10   0.31622776601683794f
#define RS100  0.1f
#define RS128  0.08838834764831845f
#define RS64   0.125f
#define RS192  0.07216878364870323f
#define RS3    0.5773502691896258f
#define RSNEI  0.31622776601683794f

typedef __bf16 bf16x8 __attribute__((ext_vector_type(8)));
typedef float  f32x4  __attribute__((ext_vector_type(4)));

__device__ __forceinline__ float bflo(unsigned u) { return __uint_as_float(u << 16); }
__device__ __forceinline__ float bfhi(unsigned u) { return __uint_as_float(u & 0xffff0000u); }

// ---------------------------------------------------------------------------
// Kernel 1: sender transform -> lane-blocked s_pack[a][64][6] bf16 (proven R8/R9)
// ---------------------------------------------------------------------------
__global__ __launch_bounds__(320) void sender_kernel(
    const float* __restrict__ sender_input, const float* __restrict__ sender_attr,
    const float* __restrict__ lin1_w0, const float* __restrict__ lin1_w1,
    __bf16* __restrict__ s_pack)
{
    __shared__ float sin_s[DIM];
    const int a = blockIdx.x;
    const int t = threadIdx.x;
    const float attr = sender_attr[a];
    sin_s[t] = sender_input[(size_t)a * DIM + t] * attr;
    __syncthreads();
    __bf16* row = s_pack + (size_t)a * 384;
    if (t < MUL0) {
        float acc = 0.f;
        for (int u = 0; u < MUL0; ++u)
            acc = fmaf(sin_s[u], lin1_w0[u * MUL0 + t], acc);
        row[(t & 63) * 6 + (t >> 6)] = (__bf16)(acc * RS128);
    } else {
        const int idx = t - MUL0;
        const int v = idx / 3, m = idx - 3 * v;
        float acc = 0.f;
        for (int u = 0; u < MUL1; ++u)
            acc = fmaf(sin_s[MUL0 + 3 * u + m], lin1_w1[u * MUL1 + v], acc);
        row[v * 6 + 2 + m] = (__bf16)(acc * RS64);
    }
    if (t < 64) row[t * 6 + 5] = (__bf16)0.f;
}

// ---------------------------------------------------------------------------
// CSR build: histogram -> scan -> scatter (+ permuted src/attr) (proven R8/R9)
// ---------------------------------------------------------------------------
__global__ __launch_bounds__(256) void hist_kernel(
    const int* __restrict__ edge_dst, int* __restrict__ counts)
{
    const int e = blockIdx.x * 256 + threadIdx.x;
    if (e < E_N) atomicAdd(&counts[edge_dst[e]], 1);
}

__global__ __launch_bounds__(1024) void scan_kernel(
    const int* __restrict__ counts, int* __restrict__ head)
{
    __shared__ int part[1024];
    const int t = threadIdx.x;
    const int base = t * 20;
    int c[20];
    int s = 0;
    #pragma unroll
    for (int i = 0; i < 20; ++i) {
        const int p = base + i;
        c[i] = (p < P_N) ? counts[p] : 0;
        s += c[i];
    }
    part[t] = s;
    __syncthreads();
    for (int off = 1; off < 1024; off <<= 1) {
        const int v = (t >= off) ? part[t - off] : 0;
        __syncthreads();
        part[t] += v;
        __syncthreads();
    }
    int run = (t > 0) ? part[t - 1] : 0;
    #pragma unroll
    for (int i = 0; i < 20; ++i) {
        const int p = base + i;
        if (p < P_N) { head[p] = run; run += c[i]; }
    }
}

__global__ __launch_bounds__(256) void scatter_kernel(
    const int* __restrict__ edge_dst, const int* __restrict__ edge_src,
    const float4* __restrict__ edge_attr4,
    int* __restrict__ head, int* __restrict__ sorted,
    int* __restrict__ src_sorted, float4* __restrict__ attr_sorted)
{
    const int e = blockIdx.x * 256 + threadIdx.x;
    if (e < E_N) {
        const int pos = atomicAdd(&head[edge_dst[e]], 1);
        sorted[pos]      = e;
        src_sorted[pos]  = edge_src[e];
        attr_sorted[pos] = edge_attr4[e];
    }
}

// ---------------------------------------------------------------------------
// pack_w2: fc_w2 -> bf16 MFMA B-fragment order (proven R6-R9). RS100 folded.
// ---------------------------------------------------------------------------
__global__ __launch_bounds__(256) void pack_w2_kernel(
    const float* __restrict__ fc_w2, __bf16* __restrict__ w2p)
{
    const int tid  = blockIdx.x * 256 + threadIdx.x;
    const int lane = tid & 63;
    const int g    = (tid >> 6) & 3;
    const int n    = tid >> 8;
    const int col  = n * 16 + (lane & 15);
    const int kb   = g * 32 + 8 * (lane >> 4);
    bf16x8 v;
    #pragma unroll
    for (int i = 0; i < 8; ++i) {
        const int k = kb + i;
        v[i] = (__bf16)((k < FC_HID) ? fc_w2[k * WNUM + col] * RS100 : 0.f);
    }
    ((bf16x8*)w2p)[tid] = v;
}

// ---------------------------------------------------------------------------
// Generic pack (proven R7-R9): src [K][N] f32 -> bf16 B-fragment order.
// ---------------------------------------------------------------------------
__global__ __launch_bounds__(256) void pack_kernel(
    const float* __restrict__ src, __bf16* __restrict__ dst,
    int K, int KG, int N, float scale)
{
    const int tid  = blockIdx.x * 256 + threadIdx.x;
    const int lane = tid & 63;
    const int fi   = tid >> 6;
    const int g    = fi % KG;
    const int n    = fi / KG;
    const int col  = n * 16 + (lane & 15);
    const int kb   = g * 32 + 8 * (lane >> 4);
    bf16x8 v;
    #pragma unroll
    for (int i = 0; i < 8; ++i) {
        const int k = kb + i;
        v[i] = (__bf16)((k < K) ? src[(size_t)k * N + col] * scale : 0.f);
    }
    ((bf16x8*)dst)[tid] = v;
}

// ---------------------------------------------------------------------------
// Kernel A (rewritten stores): MLP + weight MFMA-GEMM over one chunk.
// Changes vs R9 (values identical):
//  - fc1s XOR-swizzled (k ^ ((k&96)>>3)): kills the 4-way bank conflict on
//    every h-phase read (all k0 groups hit distinct banks).
//  - es_s padded [64][11].
//  - C stores staged through LDS in 2 halves of 32 rows: frags -> lane-blocked
//    stage (24 KB) -> fully coalesced 96 B/thread global stores. Kills the
//    2.7x HBM write amplification of the old 2B-strided stores.
// ---------------------------------------------------------------------------
__global__ __launch_bounds__(256) void mlp_gemm_chunk_kernel(
    const int* __restrict__ sorted,
    const float* __restrict__ edge_scalars,
    const float* __restrict__ fc_w1, const __bf16* __restrict__ w2p,
    __bf16* __restrict__ wbuf, int cLo)
{
    __shared__ float  fc1s[NBASIS * 128];      // 5 KB, swizzled
    __shared__ float  es_s[64][11];            // 2.75 KB, padded
    __shared__ int    eid_s[64];
    __shared__ __attribute__((aligned(16))) __bf16 hstage[32 * 384]; // 24 KB
    // phase A: h_lds = hstage[0 .. 64*128)  (16 KB)
    // phase B: stage[32 rows][384] lane-blocked (24 KB)

    const int tid   = threadIdx.x;
    const int wave  = tid >> 6;
    const int lane  = tid & 63;
    const int pbase = blockIdx.x * 64;

    if (tid < 64) {
        int gi = cLo + pbase + tid;
        if (gi >= E_N) gi = E_N - 1;
        eid_s[tid] = sorted[gi];
    }
    for (int f = tid; f < NBASIS * FC_HID; f += 256) {
        const int i = f / FC_HID, k = f - i * FC_HID;
        fc1s[i * 128 + (k ^ ((k & 96) >> 3))] = fc_w1[f];
    }
    __syncthreads();

    for (int f = tid; f < 64 * NBASIS; f += 256) {
        const int e = f / NBASIS, i = f - e * NBASIS;
        es_s[e][i] = edge_scalars[(size_t)eid_s[e] * NBASIS + i];
    }
    __syncthreads();

    // h: thread t -> edge t>>2, k-range (t&3)*32..+31; silu; bf16 -> h_lds
    __bf16* h_lds = hstage;
    {
        const int e  = tid >> 2;
        const int k0 = (tid & 3) * 32;
        const int kx = (tid & 3) * 4;          // (k0 & 96) >> 3
        float es[NBASIS];
        #pragma unroll
        for (int i = 0; i < NBASIS; ++i) es[i] = es_s[e][i];
        #pragma unroll
        for (int o = 0; o < 4; ++o) {
            bf16x8 hv;
            #pragma unroll
            for (int j = 0; j < 8; ++j) {
                const int r = o * 8 + j;
                const int k = k0 + r;
                float x = 0.f;
                if (k < FC_HID) {
                    const int ks = k0 + (r ^ kx);   // swizzled index
                    #pragma unroll
                    for (int i = 0; i < NBASIS; ++i)
                        x = fmaf(es[i], fc1s[i * 128 + ks], x);
                    x *= RS10;
                    x = x / (1.f + __expf(-x));
                }
                hv[j] = (__bf16)x;
            }
            const int idx = (e * 128 + k0 + o * 8) ^ ((e & 7) << 3);
            *(bf16x8*)&h_lds[idx] = hv;
        }
    }
    __syncthreads();

    // A frags -> registers (proven R6-R9 layout)
    bf16x8 a[4][4];
    const int arow = lane & 15, ag = lane >> 4;
    #pragma unroll
    for (int mt = 0; mt < 4; ++mt) {
        const int e = mt * 16 + arow;
        #pragma unroll
        for (int g = 0; g < 4; ++g) {
            const int idx = (e * 128 + g * 32 + ag * 8) ^ ((e & 7) << 3);
            a[mt][g] = *(const bf16x8*)&h_lds[idx];
        }
    }

    const bf16x8* w2v = (const bf16x8*)w2p;
    const int row0 = 4 * (lane >> 4), col16 = lane & 15;

    #pragma unroll
    for (int half = 0; half < 2; ++half) {
        __syncthreads();   // h reads done (half 0) / prev half stored (half 1)
        for (int nt = 0; nt < 6; ++nt) {
            const int ntile = wave * 6 + nt;
            bf16x8 b[4];
            #pragma unroll
            for (int g = 0; g < 4; ++g)
                b[g] = w2v[(ntile * 4 + g) * 64 + lane];
            const int L = ntile * 16 + col16;
            const int slot = (L & 63) * 6 + (L >> 6);   // lane-blocked slot
            #pragma unroll
            for (int mtl = 0; mtl < 2; ++mtl) {
                const int mt = half * 2 + mtl;
                f32x4 acc = {0.f, 0.f, 0.f, 0.f};
                #pragma unroll
                for (int g = 0; g < 4; ++g)
                    acc = __builtin_amdgcn_mfma_f32_16x16x32_bf16(a[mt][g], b[g],
                                                                  acc, 0, 0, 0);
                __bf16* sp = &hstage[(mtl * 16 + row0) * 384 + slot];
                #pragma unroll
                for (int j = 0; j < 4; ++j)
                    sp[j * 384] = (__bf16)acc[j];
            }
        }
        __syncthreads();   // stage complete
        // coalesced store: 32 rows x 768B; 8 threads/row, 96B each
        const int srow = tid >> 3;
        const float4* sp4 = (const float4*)&hstage[srow * 384 + (tid & 7) * 48];
        float4* gp4 = (float4*)((char*)wbuf
                      + (size_t)(pbase + half * 32 + srow) * 768
                      + (size_t)(tid & 7) * 96);
        #pragma unroll
        for (int q = 0; q < 6; ++q) gp4[q] = sp4[q];
    }
}

// ---------------------------------------------------------------------------
// Kernel B (slim gather, proven R9): consume loop -> rbuf/rinp bf16 + angle.
// ---------------------------------------------------------------------------
__global__ __launch_bounds__(256) void gather_kernel(
    const int* __restrict__ head, const int* __restrict__ counts,
    const int* __restrict__ src_sorted, const float4* __restrict__ attr_sorted,
    const __bf16* __restrict__ wbuf, const __bf16* __restrict__ s_pack,
    const float* __restrict__ receiver_input, const float* __restrict__ receiver_attr,
    const float* __restrict__ lin3_w,
    __bf16* __restrict__ rbuf, __bf16* __restrict__ rinp,
    float* __restrict__ cs_arr, float* __restrict__ sn_arr,
    int cLo, int cHi)
{
    __shared__ int sel_s[4];
    const int tid  = threadIdx.x;
    const int wave = tid >> 6;
    const int lane = tid & 63;
    const int p = blockIdx.x * 4 + wave;

    const int cnt   = counts[p];
    const int start = head[p] - cnt;
    const int sel   = (start >= cLo) & (start < cHi);

    if (lane == 0) sel_s[wave] = sel;
    __syncthreads();
    if ((sel_s[0] | sel_s[1] | sel_s[2] | sel_s[3]) == 0) return;
    if (!sel) return;   // no barriers below -> per-wave exit is safe

    float acc[12];
    #pragma unroll
    for (int i = 0; i < 12; ++i) acc[i] = 0.f;

    #pragma unroll 2
    for (int i = 0; i < cnt; ++i) {
        const int pos = start + i;
        const unsigned* wq = (const unsigned*)((const char*)wbuf
                             + (size_t)(pos - cLo) * 768 + lane * 12);
        const int    src = src_sorted[pos];
        const float4 ea  = attr_sorted[pos];
        const unsigned* sq = (const unsigned*)((const char*)s_pack
                             + (size_t)src * 768 + lane * 12);
        const unsigned w01 = wq[0], w23 = wq[1], w45 = wq[2];
        const unsigned s01 = sq[0], s23 = sq[1], s45 = sq[2];

        const float sh0 = ea.x, sh1x = ea.y, sh1y = ea.z, sh1z = ea.w;
        const float w0a = bflo(w01), w0b = bfhi(w01);
        const float w1a = bflo(w23), w1b = bfhi(w23);
        const float w2v = bflo(w45), w3v = bfhi(w45);
        const float g0a = bflo(s01), g0b = bfhi(s01);
        const float g1x = bflo(s23), g1y = bfhi(s23), g1z = bflo(s45);

        acc[0] = fmaf(w0a * g0a, sh0, acc[0]);
        acc[1] = fmaf(w0b * g0b, sh0, acc[1]);
        const float dotg = fmaf(g1x, sh1x, fmaf(g1y, sh1y, g1z * sh1z)) * RS3;
        acc[2] = fmaf(w3v, dotg, acc[2]);
        const float p1a = w1a * g0a, p1b = w1b * g0b;
        acc[3] = fmaf(p1a, sh1x, acc[3]);
        acc[4] = fmaf(p1a, sh1y, acc[4]);
        acc[5] = fmaf(p1a, sh1z, acc[5]);
        acc[6] = fmaf(p1b, sh1x, acc[6]);
        acc[7] = fmaf(p1b, sh1y, acc[7]);
        acc[8] = fmaf(p1b, sh1z, acc[8]);
        const float q = w2v * sh0;
        acc[9]  = fmaf(q, g1x, acc[9]);
        acc[10] = fmaf(q, g1y, acc[10]);
        acc[11] = fmaf(q, g1z, acc[11]);
    }

    const float rattr = receiver_attr[p];
    const float rfac  = RSNEI * rattr;
    const float v0 = acc[0] * rfac, v1 = acc[1] * rfac, v2 = acc[2] * rfac;

    // angle: per-lane partial over the 192 r0 entries, 64-lane butterfly
    float part = v0 * lin3_w[lane] + v1 * lin3_w[64 + lane] + v2 * lin3_w[128 + lane];
    #pragma unroll
    for (int off = 1; off < 64; off <<= 1) part += __shfl_xor(part, off);
    if (lane == 0) {
        const float a = part * 0.1f * RS192;
        cs_arr[p] = __cosf(a);
        sn_arr[p] = __sinf(a);
    }

    __bf16* rb = rbuf + (size_t)p * 768;
    rb[lane]       = (__bf16)v0;
    rb[64 + lane]  = (__bf16)v1;
    rb[128 + lane] = (__bf16)v2;
    #pragma unroll
    for (int m = 0; m < 3; ++m) {
        __bf16* r1 = rb + 192 + m * 192;
        r1[lane]        = (__bf16)(acc[3 + m] * rfac);
        r1[64 + lane]   = (__bf16)(acc[6 + m] * rfac);
        r1[128 + lane]  = (__bf16)(acc[9 + m] * rfac);
    }

    // rin pack (rattr folded)
    __bf16* rp = rinp + (size_t)p * 320;
    #pragma unroll
    for (int q = 0; q < 5; ++q) {
        const int t = q * 64 + lane;
        const float val = receiver_input[(size_t)p * DIM + t] * rattr;
        int pos;
        if (t < 128) pos = t;
        else { const int idx = t - 128; const int u = idx / 3, m = idx - 3 * u;
               pos = 128 + m * 64 + u; }
        rp[pos] = (__bf16)val;
    }
}

// ---------------------------------------------------------------------------
// Kernel C (proven R9): output transform, pure MFMA, no LDS/barriers.
// ---------------------------------------------------------------------------
__global__ __launch_bounds__(256) void out_transform_kernel(
    const __bf16* __restrict__ rbuf, const __bf16* __restrict__ rinp,
    const __bf16* __restrict__ scw0p, const __bf16* __restrict__ l2w0p,
    const __bf16* __restrict__ scw1p, const __bf16* __restrict__ l2w1p,
    const float* __restrict__ cs_arr, const float* __restrict__ sn_arr,
    float* __restrict__ out)
{
    const int wave = threadIdx.x >> 6, lane = threadIdx.x & 63;
    const int pw0 = blockIdx.x * 64 + wave * 16;
    const int arow = lane & 15, ag = lane >> 4;
    const int crow0 = 4 * (lane >> 4), ccol = lane & 15;

    const size_t riRow = (size_t)(pw0 + arow) * 320;
    const size_t rbRow = (size_t)(pw0 + arow) * 768;

    float cs[4], sn[4];
    #pragma unroll
    for (int j = 0; j < 4; ++j) {
        cs[j] = cs_arr[pw0 + crow0 + j];
        sn[j] = sn_arr[pw0 + crow0 + j];
    }

    // ---- scalar part: out cols 0..127 ----
    {
        bf16x8 ain[4], arr[6];
        #pragma unroll
        for (int g = 0; g < 4; ++g)
            ain[g] = *(const bf16x8*)&rinp[riRow + g * 32 + ag * 8];
        #pragma unroll
        for (int g = 0; g < 6; ++g)
            arr[g] = *(const bf16x8*)&rbuf[rbRow + g * 32 + ag * 8];
        #pragma unroll
        for (int nt = 0; nt < 8; ++nt) {
            f32x4 asc = {0.f, 0.f, 0.f, 0.f}, acv = {0.f, 0.f, 0.f, 0.f};
            #pragma unroll
            for (int g = 0; g < 4; ++g)
                asc = __builtin_amdgcn_mfma_f32_16x16x32_bf16(
                    ain[g], ((const bf16x8*)scw0p)[(nt * 4 + g) * 64 + lane], asc, 0, 0, 0);
            #pragma unroll
            for (int g = 0; g < 6; ++g)
                acv = __builtin_amdgcn_mfma_f32_16x16x32_bf16(
                    arr[g], ((const bf16x8*)l2w0p)[(nt * 6 + g) * 64 + lane], acv, 0, 0, 0);
            #pragma unroll
            for (int j = 0; j < 4; ++j) {
                const int row = pw0 + crow0 + j;
                if (row < P_N)
                    out[(size_t)row * DIM + nt * 16 + ccol] =
                        cs[j] * asc[j] + sn[j] * acv[j];
            }
        }
    }
    // ---- vector part: out cols 128 + 3v + m ----
    #pragma unroll
    for (int m = 0; m < 3; ++m) {
        bf16x8 ain1[2], arr1[6];
        #pragma unroll
        for (int g = 0; g < 2; ++g)
            ain1[g] = *(const bf16x8*)&rinp[riRow + 128 + m * 64 + g * 32 + ag * 8];
        #pragma unroll
        for (int g = 0; g < 6; ++g)
            arr1[g] = *(const bf16x8*)&rbuf[rbRow + 192 + m * 192 + g * 32 + ag * 8];
        #pragma unroll
        for (int vt = 0; vt < 4; ++vt) {
            f32x4 asc = {0.f, 0.f, 0.f, 0.f}, acv = {0.f, 0.f, 0.f, 0.f};
            #pragma unroll
            for (int g = 0; g < 2; ++g)
                asc = __builtin_amdgcn_mfma_f32_16x16x32_bf16(
                    ain1[g], ((const bf16x8*)scw1p)[(vt * 2 + g) * 64 + lane], asc, 0, 0, 0);
            #pragma unroll
            for (int g = 0; g < 6; ++g)
                acv = __builtin_amdgcn_mfma_f32_16x16x32_bf16(
                    arr1[g], ((const bf16x8*)l2w1p)[(vt * 6 + g) * 64 + lane], acv, 0, 0, 0);
            #pragma unroll
            for (int j = 0; j < 4; ++j) {
                const int row = pw0 + crow0 + j;
                if (row < P_N) {
                    const int v = vt * 16 + ccol;
                    out[(size_t)row * DIM + MUL0 + 3 * v + m] =
                        cs[j] * asc[j] + sn[j] * acv[j];
                }
            }
        }
    }
}

// ---------------------------------------------------------------------------
extern "C" void kernel_launch(void* const* d_in, const int* in_sizes, int n_in,
                              void* d_out, int out_size, void* d_ws, size_t ws_size,
                              hipStream_t stream)
{
    const float* sender_input   = (const float*)d_in[0];
    const float* sender_attr    = (const float*)d_in[1];
    const float* receiver_input = (const float*)d_in[2];
    const float* receiver_attr  = (const float*)d_in[3];
    const int*   edge_src       = (const int*)  d_in[4];
    const int*   edge_dst       = (const int*)  d_in[5];
    const float* edge_attr      = (const float*)d_in[6];
    const float* edge_scalars   = (const float*)d_in[7];
    const float* fc_w1          = (const float*)d_in[8];
    const float* fc_w2          = (const float*)d_in[9];
    const float* lin1_w0        = (const float*)d_in[10];
    const float* lin1_w1        = (const float*)d_in[11];
    const float* sc_w0          = (const float*)d_in[12];
    const float* sc_w1          = (const float*)d_in[13];
    const float* lin2_w0        = (const float*)d_in[14];
    const float* lin2_w1        = (const float*)d_in[15];
    const float* lin3_w         = (const float*)d_in[16];
    float* out = (float*)d_out;

    // ws layout: fixed buffers first, wbuf takes the remainder.
    char* wsb = (char*)d_ws;
    float4* attr_sorted = (float4*)wsb;                                   // 3.20 MB
    __bf16* s_pack = (__bf16*)(wsb + (size_t)E_N * 16);                   // 1.54 MB
    __bf16* w2p    = s_pack + (size_t)A_N * 384;                          // 96 KB
    __bf16* scw0p  = w2p   + 24 * 4 * 64 * 8;
    __bf16* l2w0p  = scw0p +  8 * 4 * 64 * 8;
    __bf16* scw1p  = l2w0p +  8 * 6 * 64 * 8;
    __bf16* l2w1p  = scw1p +  4 * 2 * 64 * 8;
    __bf16* rbuf   = l2w1p +  4 * 6 * 64 * 8;                             // 30.8 MB
    __bf16* rinp   = rbuf + (size_t)PPAD * 768;                           // 12.8 MB
    float*  cs_arr = (float*)(rinp + (size_t)PPAD * 320);
    float*  sn_arr = cs_arr + PPAD;
    int* counts     = (int*)(sn_arr + PPAD);
    int* head       = counts + P_N;
    int* sorted     = head + P_N;
    int* src_sorted = sorted + E_N;
    __bf16* wbuf    = (__bf16*)(src_sorted + E_N);
    const size_t fixedB = (size_t)((char*)wbuf - wsb);

    // dynamic chunk size from remaining workspace
    long long maxpos = (long long)((ws_size - fixedB) / 768);
    long long cc = (maxpos - OV - 64) & ~63LL;
    int cchunk = (cc > E_N) ? E_N : (int)cc;

    sender_kernel<<<A_N, 320, 0, stream>>>(sender_input, sender_attr,
                                           lin1_w0, lin1_w1, s_pack);
    pack_w2_kernel<<<24, 256, 0, stream>>>(fc_w2, w2p);
    pack_kernel<<< 8, 256, 0, stream>>>(sc_w0,   scw0p, 128, 4, 128, RS128);
    pack_kernel<<<12, 256, 0, stream>>>(lin2_w0, l2w0p, 192, 6, 128, RS192);
    pack_kernel<<< 2, 256, 0, stream>>>(sc_w1,   scw1p, 64,  2, 64,  RS64);
    pack_kernel<<< 6, 256, 0, stream>>>(lin2_w1, l2w1p, 192, 6, 64,  RS192);

    hipMemsetAsync(counts, 0, P_N * sizeof(int), stream);
    hist_kernel<<<(E_N + 255) / 256, 256, 0, stream>>>(edge_dst, counts);
    scan_kernel<<<1, 1024, 0, stream>>>(counts, head);
    scatter_kernel<<<(E_N + 255) / 256, 256, 0, stream>>>(
        edge_dst, edge_src, (const float4*)edge_attr,
        head, sorted, src_sorted, attr_sorted);

    for (int cLo = 0; cLo < E_N; cLo += cchunk) {
        int nPos = E_N - cLo;
        if (nPos > cchunk + OV) nPos = cchunk + OV;
        const int cHi = (cLo + cchunk >= E_N) ? (E_N + 1) : (cLo + cchunk);
        mlp_gemm_chunk_kernel<<<(nPos + 63) / 64, 256, 0, stream>>>(
            sorted, edge_scalars, fc_w1, w2p, wbuf, cLo);
        gather_kernel<<<P_N / 4, 256, 0, stream>>>(
            head, counts, src_sorted, attr_sorted, wbuf, s_pack,
            receiver_input, receiver_attr, lin3_w,
            rbuf, rinp, cs_arr, sn_arr, cLo, cHi);
    }

    out_transform_kernel<<<(P_N + 63) / 64, 256, 0, stream>>>(
        rbuf, rinp, scw0p, l2w0p, scw1p, l2w1p, cs_arr, sn_arr, out);
}

// Round 11
// 244.702 us; speedup vs baseline: 2.8911x; 1.0012x over previous
//
#include <hip/hip_runtime.h>
#include <hip/hip_bf16.h>
#include <math.h>

// Problem constants
#define A_N    2000
#define P_N    20000
#define PPAD   20032   // P_N padded to 64 rows (out_transform tail)
#define E_N    200000
#define MUL0   128
#define MUL1   64
#define DIM    320     // MUL0 + 3*MUL1
#define NBASIS 10
#define FC_HID 100
#define WNUM   384     // 128+128+64+64
#define MID0   192     // MUL0 + MUL1
#define OV     128     // > max edges per receiver (Poisson(10), max ~30)
#define SSTRIDE 392    // stage row stride (bf16): 784 B, 16B-aligned, 4-bank shift

// scales
#define RS10   0.31622776601683794f
#define RS100  0.1f
#define RS128  0.08838834764831845f
#define RS64   0.125f
#define RS192  0.07216878364870323f
#define RS3    0.5773502691896258f
#define RSNEI  0.31622776601683794f

typedef __bf16 bf16x8 __attribute__((ext_vector_type(8)));
typedef float  f32x4  __attribute__((ext_vector_type(4)));

__device__ __forceinline__ float bflo(unsigned u) { return __uint_as_float(u << 16); }
__device__ __forceinline__ float bfhi(unsigned u) { return __uint_as_float(u & 0xffff0000u); }

// ---------------------------------------------------------------------------
// Kernel 1: sender transform -> lane-blocked s_pack[a][64][6] bf16 (proven R8-R10)
// ---------------------------------------------------------------------------
__global__ __launch_bounds__(320) void sender_kernel(
    const float* __restrict__ sender_input, const float* __restrict__ sender_attr,
    const float* __restrict__ lin1_w0, const float* __restrict__ lin1_w1,
    __bf16* __restrict__ s_pack)
{
    __shared__ float sin_s[DIM];
    const int a = blockIdx.x;
    const int t = threadIdx.x;
    const float attr = sender_attr[a];
    sin_s[t] = sender_input[(size_t)a * DIM + t] * attr;
    __syncthreads();
    __bf16* row = s_pack + (size_t)a * 384;
    if (t < MUL0) {
        float acc = 0.f;
        for (int u = 0; u < MUL0; ++u)
            acc = fmaf(sin_s[u], lin1_w0[u * MUL0 + t], acc);
        row[(t & 63) * 6 + (t >> 6)] = (__bf16)(acc * RS128);
    } else {
        const int idx = t - MUL0;
        const int v = idx / 3, m = idx - 3 * v;
        float acc = 0.f;
        for (int u = 0; u < MUL1; ++u)
            acc = fmaf(sin_s[MUL0 + 3 * u + m], lin1_w1[u * MUL1 + v], acc);
        row[v * 6 + 2 + m] = (__bf16)(acc * RS64);
    }
    if (t < 64) row[t * 6 + 5] = (__bf16)0.f;
}

// ---------------------------------------------------------------------------
// CSR build: histogram -> scan -> scatter (+ permuted src/attr) (proven R8-R10)
// ---------------------------------------------------------------------------
__global__ __launch_bounds__(256) void hist_kernel(
    const int* __restrict__ edge_dst, int* __restrict__ counts)
{
    const int e = blockIdx.x * 256 + threadIdx.x;
    if (e < E_N) atomicAdd(&counts[edge_dst[e]], 1);
}

__global__ __launch_bounds__(1024) void scan_kernel(
    const int* __restrict__ counts, int* __restrict__ head)
{
    __shared__ int part[1024];
    const int t = threadIdx.x;
    const int base = t * 20;
    int c[20];
    int s = 0;
    #pragma unroll
    for (int i = 0; i < 20; ++i) {
        const int p = base + i;
        c[i] = (p < P_N) ? counts[p] : 0;
        s += c[i];
    }
    part[t] = s;
    __syncthreads();
    for (int off = 1; off < 1024; off <<= 1) {
        const int v = (t >= off) ? part[t - off] : 0;
        __syncthreads();
        part[t] += v;
        __syncthreads();
    }
    int run = (t > 0) ? part[t - 1] : 0;
    #pragma unroll
    for (int i = 0; i < 20; ++i) {
        const int p = base + i;
        if (p < P_N) { head[p] = run; run += c[i]; }
    }
}

__global__ __launch_bounds__(256) void scatter_kernel(
    const int* __restrict__ edge_dst, const int* __restrict__ edge_src,
    const float4* __restrict__ edge_attr4,
    int* __restrict__ head, int* __restrict__ sorted,
    int* __restrict__ src_sorted, float4* __restrict__ attr_sorted)
{
    const int e = blockIdx.x * 256 + threadIdx.x;
    if (e < E_N) {
        const int pos = atomicAdd(&head[edge_dst[e]], 1);
        sorted[pos]      = e;
        src_sorted[pos]  = edge_src[e];
        attr_sorted[pos] = edge_attr4[e];
    }
}

// ---------------------------------------------------------------------------
// pack_w2: fc_w2 -> bf16 MFMA B-fragment order (proven R6-R10). RS100 folded.
// ---------------------------------------------------------------------------
__global__ __launch_bounds__(256) void pack_w2_kernel(
    const float* __restrict__ fc_w2, __bf16* __restrict__ w2p)
{
    const int tid  = blockIdx.x * 256 + threadIdx.x;
    const int lane = tid & 63;
    const int g    = (tid >> 6) & 3;
    const int n    = tid >> 8;
    const int col  = n * 16 + (lane & 15);
    const int kb   = g * 32 + 8 * (lane >> 4);
    bf16x8 v;
    #pragma unroll
    for (int i = 0; i < 8; ++i) {
        const int k = kb + i;
        v[i] = (__bf16)((k < FC_HID) ? fc_w2[k * WNUM + col] * RS100 : 0.f);
    }
    ((bf16x8*)w2p)[tid] = v;
}

// ---------------------------------------------------------------------------
// Generic pack (proven R7-R10): src [K][N] f32 -> bf16 B-fragment order.
// ---------------------------------------------------------------------------
__global__ __launch_bounds__(256) void pack_kernel(
    const float* __restrict__ src, __bf16* __restrict__ dst,
    int K, int KG, int N, float scale)
{
    const int tid  = blockIdx.x * 256 + threadIdx.x;
    const int lane = tid & 63;
    const int fi   = tid >> 6;
    const int g    = fi % KG;
    const int n    = fi / KG;
    const int col  = n * 16 + (lane & 15);
    const int kb   = g * 32 + 8 * (lane >> 4);
    bf16x8 v;
    #pragma unroll
    for (int i = 0; i < 8; ++i) {
        const int k = kb + i;
        v[i] = (__bf16)((k < K) ? src[(size_t)k * N + col] * scale : 0.f);
    }
    ((bf16x8*)dst)[tid] = v;
}

// ---------------------------------------------------------------------------
// Kernel A: MLP + weight MFMA-GEMM over one chunk (proven R10 body).
// R11 deltas: stage stride 392 (bank-shift 4, 16B-aligned -> kills stage-write
// 4-way conflict); es gather issues at t=0 direct from sorted (no eid_s LDS,
// one less barrier); #pragma unroll 2 on nt loop batches B-frag loads.
// ---------------------------------------------------------------------------
__global__ __launch_bounds__(256) void mlp_gemm_chunk_kernel(
    const int* __restrict__ sorted,
    const float* __restrict__ edge_scalars,
    const float* __restrict__ fc_w1, const __bf16* __restrict__ w2p,
    __bf16* __restrict__ wbuf, int cLo)
{
    __shared__ float  fc1s[NBASIS * 128];      // 5 KB, swizzled
    __shared__ float  es_s[64][11];            // 2.75 KB, padded
    __shared__ __attribute__((aligned(16))) __bf16 hstage[32 * SSTRIDE]; // 24.5 KB
    // phase A: h_lds = hstage[0 .. 64*128)  (16 KB)
    // phase B: stage[32 rows][SSTRIDE] lane-blocked

    const int tid   = threadIdx.x;
    const int wave  = tid >> 6;
    const int lane  = tid & 63;
    const int pbase = blockIdx.x * 64;

    // es gather first (longest latency), fc1s staged concurrently
    for (int f = tid; f < 64 * NBASIS; f += 256) {
        const int e = f / NBASIS, i = f - e * NBASIS;
        int gi = cLo + pbase + e;
        if (gi >= E_N) gi = E_N - 1;           // pad rows never consumed
        es_s[e][i] = edge_scalars[(size_t)sorted[gi] * NBASIS + i];
    }
    for (int f = tid; f < NBASIS * FC_HID; f += 256) {
        const int i = f / FC_HID, k = f - i * FC_HID;
        fc1s[i * 128 + (k ^ ((k & 96) >> 3))] = fc_w1[f];
    }
    __syncthreads();

    // h: thread t -> edge t>>2, k-range (t&3)*32..+31; silu; bf16 -> h_lds
    __bf16* h_lds = hstage;
    {
        const int e  = tid >> 2;
        const int k0 = (tid & 3) * 32;
        const int kx = (tid & 3) * 4;          // (k0 & 96) >> 3
        float es[NBASIS];
        #pragma unroll
        for (int i = 0; i < NBASIS; ++i) es[i] = es_s[e][i];
        #pragma unroll
        for (int o = 0; o < 4; ++o) {
            bf16x8 hv;
            #pragma unroll
            for (int j = 0; j < 8; ++j) {
                const int r = o * 8 + j;
                const int k = k0 + r;
                float x = 0.f;
                if (k < FC_HID) {
                    const int ks = k0 + (r ^ kx);   // swizzled index
                    #pragma unroll
                    for (int i = 0; i < NBASIS; ++i)
                        x = fmaf(es[i], fc1s[i * 128 + ks], x);
                    x *= RS10;
                    x = x / (1.f + __expf(-x));
                }
                hv[j] = (__bf16)x;
            }
            const int idx = (e * 128 + k0 + o * 8) ^ ((e & 7) << 3);
            *(bf16x8*)&h_lds[idx] = hv;
        }
    }
    __syncthreads();

    // A frags -> registers (proven R6-R10 layout)
    bf16x8 a[4][4];
    const int arow = lane & 15, ag = lane >> 4;
    #pragma unroll
    for (int mt = 0; mt < 4; ++mt) {
        const int e = mt * 16 + arow;
        #pragma unroll
        for (int g = 0; g < 4; ++g) {
            const int idx = (e * 128 + g * 32 + ag * 8) ^ ((e & 7) << 3);
            a[mt][g] = *(const bf16x8*)&h_lds[idx];
        }
    }

    const bf16x8* w2v = (const bf16x8*)w2p;
    const int row0 = 4 * (lane >> 4), col16 = lane & 15;

    #pragma unroll
    for (int half = 0; half < 2; ++half) {
        __syncthreads();   // h reads done (half 0) / prev half stored (half 1)
        #pragma unroll 2
        for (int nt = 0; nt < 6; ++nt) {
            const int ntile = wave * 6 + nt;
            bf16x8 b[4];
            #pragma unroll
            for (int g = 0; g < 4; ++g)
                b[g] = w2v[(ntile * 4 + g) * 64 + lane];
            const int L = ntile * 16 + col16;
            const int slot = (L & 63) * 6 + (L >> 6);   // lane-blocked slot
            #pragma unroll
            for (int mtl = 0; mtl < 2; ++mtl) {
                const int mt = half * 2 + mtl;
                f32x4 acc = {0.f, 0.f, 0.f, 0.f};
                #pragma unroll
                for (int g = 0; g < 4; ++g)
                    acc = __builtin_amdgcn_mfma_f32_16x16x32_bf16(a[mt][g], b[g],
                                                                  acc, 0, 0, 0);
                __bf16* sp = &hstage[(mtl * 16 + row0) * SSTRIDE + slot];
                #pragma unroll
                for (int j = 0; j < 4; ++j)
                    sp[j * SSTRIDE] = (__bf16)acc[j];
            }
        }
        __syncthreads();   // stage complete
        // coalesced store: 32 rows x 768B; 8 threads/row, 96B each
        const int srow = tid >> 3;
        const float4* sp4 = (const float4*)&hstage[srow * SSTRIDE + (tid & 7) * 48];
        float4* gp4 = (float4*)((char*)wbuf
                      + (size_t)(pbase + half * 32 + srow) * 768
                      + (size_t)(tid & 7) * 96);
        #pragma unroll
        for (int q = 0; q < 6; ++q) gp4[q] = sp4[q];
    }
}

// ---------------------------------------------------------------------------
// Kernel B (slim gather, proven R9/R10 math): consume loop with depth-1
// software pipeline (wbuf/attr prefetch; src prefetched 2 ahead so the
// dependent s_pack load issues one iteration early).
// ---------------------------------------------------------------------------
__global__ __launch_bounds__(256) void gather_kernel(
    const int* __restrict__ head, const int* __restrict__ counts,
    const int* __restrict__ src_sorted, const float4* __restrict__ attr_sorted,
    const __bf16* __restrict__ wbuf, const __bf16* __restrict__ s_pack,
    const float* __restrict__ receiver_input, const float* __restrict__ receiver_attr,
    const float* __restrict__ lin3_w,
    __bf16* __restrict__ rbuf, __bf16* __restrict__ rinp,
    float* __restrict__ cs_arr, float* __restrict__ sn_arr,
    int cLo, int cHi)
{
    __shared__ int sel_s[4];
    const int tid  = threadIdx.x;
    const int wave = tid >> 6;
    const int lane = tid & 63;
    const int p = blockIdx.x * 4 + wave;

    const int cnt   = counts[p];
    const int start = head[p] - cnt;
    const int sel   = (start >= cLo) & (start < cHi);

    if (lane == 0) sel_s[wave] = sel;
    __syncthreads();
    if ((sel_s[0] | sel_s[1] | sel_s[2] | sel_s[3]) == 0) return;
    if (!sel) return;   // no barriers below -> per-wave exit is safe

    float acc[12];
    #pragma unroll
    for (int i = 0; i < 12; ++i) acc[i] = 0.f;

    if (cnt > 0) {
        const char* wb  = (const char*)wbuf;
        const char* spk = (const char*)s_pack;
        const int last = start + cnt - 1;

        // preload iteration 0
        const unsigned* wq0 = (const unsigned*)(wb + (size_t)(start - cLo) * 768 + lane * 12);
        unsigned cw0 = wq0[0], cw1 = wq0[1], cw2 = wq0[2];
        float4 cea = attr_sorted[start];
        int csrc = src_sorted[start];
        const unsigned* sq0 = (const unsigned*)(spk + (size_t)csrc * 768 + lane * 12);
        unsigned cs0 = sq0[0], cs1 = sq0[1], cs2 = sq0[2];
        int nsrc = src_sorted[(start + 1 <= last) ? start + 1 : last];

        for (int i = 0; i < cnt; ++i) {
            // issue next-iteration loads (clamped in-segment; extras cache-hit)
            const int pn = (start + i + 1 <= last) ? start + i + 1 : last;
            const unsigned* wqn = (const unsigned*)(wb + (size_t)(pn - cLo) * 768 + lane * 12);
            const unsigned nw0 = wqn[0], nw1 = wqn[1], nw2 = wqn[2];
            const float4 nea = attr_sorted[pn];
            const unsigned* sqn = (const unsigned*)(spk + (size_t)nsrc * 768 + lane * 12);
            const unsigned ns0 = sqn[0], ns1 = sqn[1], ns2 = sqn[2];
            int p2 = start + i + 2; if (p2 > last) p2 = last;
            const int nnsrc = src_sorted[p2];

            // compute with current values
            const float sh0 = cea.x, sh1x = cea.y, sh1y = cea.z, sh1z = cea.w;
            const float w0a = bflo(cw0), w0b = bfhi(cw0);
            const float w1a = bflo(cw1), w1b = bfhi(cw1);
            const float w2v = bflo(cw2), w3v = bfhi(cw2);
            const float g0a = bflo(cs0), g0b = bfhi(cs0);
            const float g1x = bflo(cs1), g1y = bfhi(cs1), g1z = bflo(cs2);

            acc[0] = fmaf(w0a * g0a, sh0, acc[0]);
            acc[1] = fmaf(w0b * g0b, sh0, acc[1]);
            const float dotg = fmaf(g1x, sh1x, fmaf(g1y, sh1y, g1z * sh1z)) * RS3;
            acc[2] = fmaf(w3v, dotg, acc[2]);
            const float p1a = w1a * g0a, p1b = w1b * g0b;
            acc[3] = fmaf(p1a, sh1x, acc[3]);
            acc[4] = fmaf(p1a, sh1y, acc[4]);
            acc[5] = fmaf(p1a, sh1z, acc[5]);
            acc[6] = fmaf(p1b, sh1x, acc[6]);
            acc[7] = fmaf(p1b, sh1y, acc[7]);
            acc[8] = fmaf(p1b, sh1z, acc[8]);
            const float q = w2v * sh0;
            acc[9]  = fmaf(q, g1x, acc[9]);
            acc[10] = fmaf(q, g1y, acc[10]);
            acc[11] = fmaf(q, g1z, acc[11]);

            // rotate pipeline
            cw0 = nw0; cw1 = nw1; cw2 = nw2;
            cs0 = ns0; cs1 = ns1; cs2 = ns2;
            cea = nea; nsrc = nnsrc;
        }
    }

    const float rattr = receiver_attr[p];
    const float rfac  = RSNEI * rattr;
    const float v0 = acc[0] * rfac, v1 = acc[1] * rfac, v2 = acc[2] * rfac;

    // angle: per-lane partial over the 192 r0 entries, 64-lane butterfly
    float part = v0 * lin3_w[lane] + v1 * lin3_w[64 + lane] + v2 * lin3_w[128 + lane];
    #pragma unroll
    for (int off = 1; off < 64; off <<= 1) part += __shfl_xor(part, off);
    if (lane == 0) {
        const float a = part * 0.1f * RS192;
        cs_arr[p] = __cosf(a);
        sn_arr[p] = __sinf(a);
    }

    __bf16* rb = rbuf + (size_t)p * 768;
    rb[lane]       = (__bf16)v0;
    rb[64 + lane]  = (__bf16)v1;
    rb[128 + lane] = (__bf16)v2;
    #pragma unroll
    for (int m = 0; m < 3; ++m) {
        __bf16* r1 = rb + 192 + m * 192;
        r1[lane]        = (__bf16)(acc[3 + m] * rfac);
        r1[64 + lane]   = (__bf16)(acc[6 + m] * rfac);
        r1[128 + lane]  = (__bf16)(acc[9 + m] * rfac);
    }

    // rin pack (rattr folded)
    __bf16* rp = rinp + (size_t)p * 320;
    #pragma unroll
    for (int q = 0; q < 5; ++q) {
        const int t = q * 64 + lane;
        const float val = receiver_input[(size_t)p * DIM + t] * rattr;
        int pos;
        if (t < 128) pos = t;
        else { const int idx = t - 128; const int u = idx / 3, m = idx - 3 * u;
               pos = 128 + m * 64 + u; }
        rp[pos] = (__bf16)val;
    }
}

// ---------------------------------------------------------------------------
// Kernel C: output transform, pure MFMA, no LDS/barriers (proven R9/R10 math).
// R11 delta: scalar and vector parts on separate blocks (grid = 2 x nbS) ->
// half the MFMA chain per wave, double TLP for this latency-exposed kernel.
// ---------------------------------------------------------------------------
__global__ __launch_bounds__(256) void out_transform_kernel(
    const __bf16* __restrict__ rbuf, const __bf16* __restrict__ rinp,
    const __bf16* __restrict__ scw0p, const __bf16* __restrict__ l2w0p,
    const __bf16* __restrict__ scw1p, const __bf16* __restrict__ l2w1p,
    const float* __restrict__ cs_arr, const float* __restrict__ sn_arr,
    float* __restrict__ out, int nbS)
{
    const int wave = threadIdx.x >> 6, lane = threadIdx.x & 63;
    const bool vec = (int)blockIdx.x >= nbS;
    const int b = vec ? (int)blockIdx.x - nbS : (int)blockIdx.x;
    const int pw0 = b * 64 + wave * 16;
    const int arow = lane & 15, ag = lane >> 4;
    const int crow0 = 4 * (lane >> 4), ccol = lane & 15;

    const size_t riRow = (size_t)(pw0 + arow) * 320;
    const size_t rbRow = (size_t)(pw0 + arow) * 768;

    float cs[4], sn[4];
    #pragma unroll
    for (int j = 0; j < 4; ++j) {
        cs[j] = cs_arr[pw0 + crow0 + j];
        sn[j] = sn_arr[pw0 + crow0 + j];
    }

    if (!vec) {
        // ---- scalar part: out cols 0..127 ----
        bf16x8 ain[4], arr[6];
        #pragma unroll
        for (int g = 0; g < 4; ++g)
            ain[g] = *(const bf16x8*)&rinp[riRow + g * 32 + ag * 8];
        #pragma unroll
        for (int g = 0; g < 6; ++g)
            arr[g] = *(const bf16x8*)&rbuf[rbRow + g * 32 + ag * 8];
        #pragma unroll
        for (int nt = 0; nt < 8; ++nt) {
            f32x4 asc = {0.f, 0.f, 0.f, 0.f}, acv = {0.f, 0.f, 0.f, 0.f};
            #pragma unroll
            for (int g = 0; g < 4; ++g)
                asc = __builtin_amdgcn_mfma_f32_16x16x32_bf16(
                    ain[g], ((const bf16x8*)scw0p)[(nt * 4 + g) * 64 + lane], asc, 0, 0, 0);
            #pragma unroll
            for (int g = 0; g < 6; ++g)
                acv = __builtin_amdgcn_mfma_f32_16x16x32_bf16(
                    arr[g], ((const bf16x8*)l2w0p)[(nt * 6 + g) * 64 + lane], acv, 0, 0, 0);
            #pragma unroll
            for (int j = 0; j < 4; ++j) {
                const int row = pw0 + crow0 + j;
                if (row < P_N)
                    out[(size_t)row * DIM + nt * 16 + ccol] =
                        cs[j] * asc[j] + sn[j] * acv[j];
            }
        }
    } else {
        // ---- vector part: out cols 128 + 3v + m ----
        #pragma unroll
        for (int m = 0; m < 3; ++m) {
            bf16x8 ain1[2], arr1[6];
            #pragma unroll
            for (int g = 0; g < 2; ++g)
                ain1[g] = *(const bf16x8*)&rinp[riRow + 128 + m * 64 + g * 32 + ag * 8];
            #pragma unroll
            for (int g = 0; g < 6; ++g)
                arr1[g] = *(const bf16x8*)&rbuf[rbRow + 192 + m * 192 + g * 32 + ag * 8];
            #pragma unroll
            for (int vt = 0; vt < 4; ++vt) {
                f32x4 asc = {0.f, 0.f, 0.f, 0.f}, acv = {0.f, 0.f, 0.f, 0.f};
                #pragma unroll
                for (int g = 0; g < 2; ++g)
                    asc = __builtin_amdgcn_mfma_f32_16x16x32_bf16(
                        ain1[g], ((const bf16x8*)scw1p)[(vt * 2 + g) * 64 + lane], asc, 0, 0, 0);
                #pragma unroll
                for (int g = 0; g < 6; ++g)
                    acv = __builtin_amdgcn_mfma_f32_16x16x32_bf16(
                        arr1[g], ((const bf16x8*)l2w1p)[(vt * 6 + g) * 64 + lane], acv, 0, 0, 0);
                #pragma unroll
                for (int j = 0; j < 4; ++j) {
                    const int row = pw0 + crow0 + j;
                    if (row < P_N) {
                        const int v = vt * 16 + ccol;
                        out[(size_t)row * DIM + MUL0 + 3 * v + m] =
                            cs[j] * asc[j] + sn[j] * acv[j];
                    }
                }
            }
        }
    }
}

// ---------------------------------------------------------------------------
extern "C" void kernel_launch(void* const* d_in, const int* in_sizes, int n_in,
                              void* d_out, int out_size, void* d_ws, size_t ws_size,
                              hipStream_t stream)
{
    const float* sender_input   = (const float*)d_in[0];
    const float* sender_attr    = (const float*)d_in[1];
    const float* receiver_input = (const float*)d_in[2];
    const float* receiver_attr  = (const float*)d_in[3];
    const int*   edge_src       = (const int*)  d_in[4];
    const int*   edge_dst       = (const int*)  d_in[5];
    const float* edge_attr      = (const float*)d_in[6];
    const float* edge_scalars   = (const float*)d_in[7];
    const float* fc_w1          = (const float*)d_in[8];
    const float* fc_w2          = (const float*)d_in[9];
    const float* lin1_w0        = (const float*)d_in[10];
    const float* lin1_w1        = (const float*)d_in[11];
    const float* sc_w0          = (const float*)d_in[12];
    const float* sc_w1          = (const float*)d_in[13];
    const float* lin2_w0        = (const float*)d_in[14];
    const float* lin2_w1        = (const float*)d_in[15];
    const float* lin3_w         = (const float*)d_in[16];
    float* out = (float*)d_out;

    // ws layout: fixed buffers first, wbuf takes the remainder.
    char* wsb = (char*)d_ws;
    float4* attr_sorted = (float4*)wsb;                                   // 3.20 MB
    __bf16* s_pack = (__bf16*)(wsb + (size_t)E_N * 16);                   // 1.54 MB
    __bf16* w2p    = s_pack + (size_t)A_N * 384;                          // 96 KB
    __bf16* scw0p  = w2p   + 24 * 4 * 64 * 8;
    __bf16* l2w0p  = scw0p +  8 * 4 * 64 * 8;
    __bf16* scw1p  = l2w0p +  8 * 6 * 64 * 8;
    __bf16* l2w1p  = scw1p +  4 * 2 * 64 * 8;
    __bf16* rbuf   = l2w1p +  4 * 6 * 64 * 8;                             // 30.8 MB
    __bf16* rinp   = rbuf + (size_t)PPAD * 768;                           // 12.8 MB
    float*  cs_arr = (float*)(rinp + (size_t)PPAD * 320);
    float*  sn_arr = cs_arr + PPAD;
    int* counts     = (int*)(sn_arr + PPAD);
    int* head       = counts + P_N;
    int* sorted     = head + P_N;
    int* src_sorted = sorted + E_N;
    __bf16* wbuf    = (__bf16*)(src_sorted + E_N);
    const size_t fixedB = (size_t)((char*)wbuf - wsb);

    // dynamic chunk size from remaining workspace (single chunk at ws>=205MB)
    long long maxpos = (long long)((ws_size - fixedB) / 768);
    long long cc = (maxpos - OV - 64) & ~63LL;
    int cchunk = (cc > E_N) ? E_N : (int)cc;

    sender_kernel<<<A_N, 320, 0, stream>>>(sender_input, sender_attr,
                                           lin1_w0, lin1_w1, s_pack);
    pack_w2_kernel<<<24, 256, 0, stream>>>(fc_w2, w2p);
    pack_kernel<<< 8, 256, 0, stream>>>(sc_w0,   scw0p, 128, 4, 128, RS128);
    pack_kernel<<<12, 256, 0, stream>>>(lin2_w0, l2w0p, 192, 6, 128, RS192);
    pack_kernel<<< 2, 256, 0, stream>>>(sc_w1,   scw1p, 64,  2, 64,  RS64);
    pack_kernel<<< 6, 256, 0, stream>>>(lin2_w1, l2w1p, 192, 6, 64,  RS192);

    hipMemsetAsync(counts, 0, P_N * sizeof(int), stream);
    hist_kernel<<<(E_N + 255) / 256, 256, 0, stream>>>(edge_dst, counts);
    scan_kernel<<<1, 1024, 0, stream>>>(counts, head);
    scatter_kernel<<<(E_N + 255) / 256, 256, 0, stream>>>(
        edge_dst, edge_src, (const float4*)edge_attr,
        head, sorted, src_sorted, attr_sorted);

    for (int cLo = 0; cLo < E_N; cLo += cchunk) {
        int nPos = E_N - cLo;
        if (nPos > cchunk + OV) nPos = cchunk + OV;
        const int cHi = (cLo + cchunk >= E_N) ? (E_N + 1) : (cLo + cchunk);
        mlp_gemm_chunk_kernel<<<(nPos + 63) / 64, 256, 0, stream>>>(
            sorted, edge_scalars, fc_w1, w2p, wbuf, cLo);
        gather_kernel<<<P_N / 4, 256, 0, stream>>>(
            head, counts, src_sorted, attr_sorted, wbuf, s_pack,
            receiver_input, receiver_attr, lin3_w,
            rbuf, rinp, cs_arr, sn_arr, cLo, cHi);
    }

    const int nbS = PPAD / 64;   // 313
    out_transform_kernel<<<2 * nbS, 256, 0, stream>>>(
        rbuf, rinp, scw0p, l2w0p, scw1p, l2w1p, cs_arr, sn_arr, out, nbS);
}